// Round 7
// baseline (434.232 us; speedup 1.0000x reference)
//
#include <hip/hip_runtime.h>
#include <cstdint>
#include <cstddef>

static constexpr int Nn = 20000;
static constexpr int Ee = 320000;
static constexpr int Npad = 20032;   // 20000 padded to x64 (313*64); 1252 row-frags

typedef _Float16 half8 __attribute__((ext_vector_type(8)));
typedef float f32x4 __attribute__((ext_vector_type(4)));

__device__ __forceinline__ float lrelu02(float x){ return fmaxf(x, 0.2f*x); }
__device__ __forceinline__ float af(int x){ return __int_as_float(x); }

// split v = hi + lo/2048, hi/lo fp16 (lo pre-scaled to stay in normal range)
__device__ __forceinline__ void packhl(float v, unsigned short& h, unsigned short& l){
  _Float16 hh = (_Float16)v;
  _Float16 ll = (_Float16)((v - (float)hh) * 2048.0f);
  h = __builtin_bit_cast(unsigned short, hh);
  l = __builtin_bit_cast(unsigned short, ll);
}

// fragment address for activation matrices [Npad][lda] (element (row,k)):
__device__ __forceinline__ size_t fragaddr(int row, int k, int lda){
  return ((size_t)(row>>4)*(lda>>3) + (k>>3))*128 + (size_t)(row&15)*8 + (k&7);
}

// ---------------- CSR build ----------------
__global__ void k_count(const int* __restrict__ dst, int* __restrict__ cnt){
  int e = blockIdx.x*256 + threadIdx.x;
  if (e < Ee) atomicAdd(&cnt[dst[e]], 1);
}

__global__ void k_scan(const int* __restrict__ cnt, int* __restrict__ row_start,
                       float* __restrict__ dinv){
  __shared__ int part[1024];
  int tid = threadIdx.x;
  const int PER = 20;
  int base = tid*PER;
  int s = 0;
  for (int i = 0; i < PER; ++i){ int idx = base+i; if (idx < Nn) s += cnt[idx]; }
  part[tid] = s; __syncthreads();
  for (int off = 1; off < 1024; off <<= 1){
    int v = (tid >= off) ? part[tid-off] : 0;
    __syncthreads();
    part[tid] += v;
    __syncthreads();
  }
  int run = (tid == 0) ? 0 : part[tid-1];
  for (int i = 0; i < PER; ++i){
    int idx = base+i;
    if (idx < Nn){
      row_start[idx] = run;
      int c = cnt[idx];
      run += c;
      dinv[idx] = rsqrtf((float)(c+1));
    }
  }
  if (tid == 1023) row_start[Nn] = run;
}

__global__ void k_scatter(const int* __restrict__ src, const int* __restrict__ dst,
                          const int* __restrict__ row_start, int* __restrict__ fill,
                          int* __restrict__ csr, const float* __restrict__ dinv,
                          int2* __restrict__ erec){
  int e = blockIdx.x*256 + threadIdx.x;
  if (e < Ee){
    int d = dst[e];
    int pos = row_start[d] + atomicAdd(&fill[d], 1);
    int u = src[e];
    csr[pos] = u;
    erec[pos] = make_int2(u, __float_as_int(dinv[u]));
  }
}

// ---------------- fragment-packed weight split ----------------
// block = (col>>4)*(K/8) + (k>>3); inner = (col&15)*8 + (k&7). hi [0,K*J), lo +K*J
template<int K, int J>
__global__ void k_packwf(const float* __restrict__ W, unsigned short* __restrict__ out){
  int i = blockIdx.x*256 + threadIdx.x;
  if (i < K*J){
    int k = i / J, col = i - k*J;
    unsigned short h, l; packhl(W[i], h, l);
    size_t pos = ((size_t)((col>>4)*(K/8) + (k>>3))*16 + (col&15))*8 + (k&7);
    out[pos] = h;
    out[pos + (size_t)K*J] = l;
  }
}

// ---------------- GCN aggregation (uniform record loads) ----------------
// POST: 0 = f32 raw; 1 = f32 relu(+bias)+skip; 2 = frag-pack raw; 3 = relu+bias+skip then frag-pack
template<int C, int POST>
__global__ __launch_bounds__(256) void k_gcn_agg(
    const float* __restrict__ h, const float* __restrict__ dinv,
    const int* __restrict__ row_start, const int2* __restrict__ erec,
    const float* __restrict__ bias, const float* __restrict__ skip,
    float* __restrict__ outf, unsigned short* __restrict__ outp){
  int v = blockIdx.x*4 + (threadIdx.x >> 6);
  int lane = threadIdx.x & 63;
  int s = __builtin_amdgcn_readfirstlane(row_start[v]);
  int e = __builtin_amdgcn_readfirstlane(row_start[v+1]);
  float dv = dinv[v];
  const int c = (C==32) ? (lane & 31) : ((C==128) ? lane*2 : lane);

  float a0 = 0.f, a1 = 0.f;
  if constexpr (C == 32){
    int half = lane >> 5;
    int j = s + half;
    for (; j + 2 < e; j += 4){
      int2 r0 = erec[j], r1 = erec[j+2];
      float t0 = h[(size_t)r0.x*32 + c];
      float t1 = h[(size_t)r1.x*32 + c];
      a0 = fmaf(af(r0.y), t0, a0);
      a0 = fmaf(af(r1.y), t1, a0);
    }
    if (j < e){
      int2 r0 = erec[j];
      a0 = fmaf(af(r0.y), h[(size_t)r0.x*32 + c], a0);
    }
    a0 += __shfl_xor(a0, 32);
  } else if constexpr (C == 128){
    int j = s;
    for (; j + 4 <= e; j += 4){
      int2 r0 = erec[j], r1 = erec[j+1], r2 = erec[j+2], r3 = erec[j+3];
      float2 t0 = *(const float2*)&h[(size_t)r0.x*128 + c];
      float2 t1 = *(const float2*)&h[(size_t)r1.x*128 + c];
      float2 t2 = *(const float2*)&h[(size_t)r2.x*128 + c];
      float2 t3 = *(const float2*)&h[(size_t)r3.x*128 + c];
      a0=fmaf(af(r0.y),t0.x,a0); a1=fmaf(af(r0.y),t0.y,a1);
      a0=fmaf(af(r1.y),t1.x,a0); a1=fmaf(af(r1.y),t1.y,a1);
      a0=fmaf(af(r2.y),t2.x,a0); a1=fmaf(af(r2.y),t2.y,a1);
      a0=fmaf(af(r3.y),t3.x,a0); a1=fmaf(af(r3.y),t3.y,a1);
    }
    for (; j < e; ++j){
      int2 r = erec[j];
      float2 t = *(const float2*)&h[(size_t)r.x*128 + c];
      a0 = fmaf(af(r.y), t.x, a0); a1 = fmaf(af(r.y), t.y, a1);
    }
  } else { // C == 64
    int j = s;
    for (; j + 4 <= e; j += 4){
      int2 r0 = erec[j], r1 = erec[j+1], r2 = erec[j+2], r3 = erec[j+3];
      float t0 = h[(size_t)r0.x*64 + c];
      float t1 = h[(size_t)r1.x*64 + c];
      float t2 = h[(size_t)r2.x*64 + c];
      float t3 = h[(size_t)r3.x*64 + c];
      a0=fmaf(af(r0.y),t0,a0); a0=fmaf(af(r1.y),t1,a0);
      a0=fmaf(af(r2.y),t2,a0); a0=fmaf(af(r3.y),t3,a0);
    }
    for (; j < e; ++j){
      int2 r = erec[j];
      a0 = fmaf(af(r.y), h[(size_t)r.x*64 + c], a0);
    }
  }

  if constexpr (C == 128){
    float2 hv = *(const float2*)&h[(size_t)v*128 + c];
    float vx = fmaf(a0, dv, hv.x*dv*dv);
    float vy = fmaf(a1, dv, hv.y*dv*dv);
    if constexpr (POST & 1){
      float2 bv = *(const float2*)&bias[c];
      float2 sk = *(const float2*)&skip[(size_t)v*128 + c];
      vx = fmaxf(vx + bv.x, 0.f) + sk.x;
      vy = fmaxf(vy + bv.y, 0.f) + sk.y;
    }
    if constexpr (POST & 2){
      unsigned short h0,l0,h1,l1; packhl(vx,h0,l0); packhl(vy,h1,l1);
      size_t a = fragaddr(v, c, 128);
      *(unsigned int*)&outp[a] = (unsigned)h0 | ((unsigned)h1<<16);
      *(unsigned int*)&outp[a + (size_t)Npad*128] = (unsigned)l0 | ((unsigned)l1<<16);
    } else {
      *(float2*)&outf[(size_t)v*128 + c] = make_float2(vx, vy);
    }
  } else if constexpr (C == 64){
    float val = fmaf(a0, dv, h[(size_t)v*64 + c]*dv*dv);
    if constexpr (POST & 1){
      val = fmaxf(val + bias[c], 0.f) + skip[(size_t)v*64 + c];
    }
    if constexpr (POST & 2){
      unsigned short hh,ll; packhl(val,hh,ll);
      size_t a = fragaddr(v, c, 64);
      outp[a] = hh;
      outp[a + (size_t)Npad*64] = ll;
    } else {
      outf[(size_t)v*64 + c] = val;
    }
  } else { // C == 32, frag-pack only
    float val = fmaf(a0, dv, h[(size_t)v*32 + c]*dv*dv);
    if (lane < 32){
      unsigned short hh,ll; packhl(val,hh,ll);
      size_t a = fragaddr(v, c, 32);
      outp[a] = hh;
      outp[a + (size_t)Npad*32] = ll;
    }
  }
}

// ---------------- fold attention vectors through W ----------------
template<int INC, int C>
__global__ void k_fold(const float* __restrict__ W, const float* __restrict__ as_,
                       const float* __restrict__ ad_, float* __restrict__ wsF,
                       float* __restrict__ wdF){
  int h = threadIdx.x >> 6, lane = threadIdx.x & 63;
  for (int k = lane; k < INC; k += 64){
    float s = 0.f, d = 0.f;
    #pragma unroll 4
    for (int c = 0; c < C; ++c){
      float wv = W[(size_t)k*(4*C) + h*C + c];
      s = fmaf(wv, as_[h*C + c], s);
      d = fmaf(wv, ad_[h*C + c], d);
    }
    wsF[h*INC + k] = s;
    wdF[h*INC + k] = d;
  }
}

// ---------------- attention coefficients from the INPUT ----------------
template<int INC>
__global__ __launch_bounds__(256) void k_attn_in(
    const float* __restrict__ X, const float* __restrict__ wsF, const float* __restrict__ wdF,
    float* __restrict__ aS, float* __restrict__ aD){
  int v = blockIdx.x*4 + (threadIdx.x >> 6);
  int lane = threadIdx.x & 63;
  float x0 = X[(size_t)v*INC + lane];
  float x1 = (INC == 128) ? X[(size_t)v*INC + 64 + lane] : 0.f;
  float s[4], d[4];
  #pragma unroll
  for (int h = 0; h < 4; ++h){
    s[h] = x0*wsF[h*INC + lane];
    d[h] = x0*wdF[h*INC + lane];
    if constexpr (INC == 128){
      s[h] = fmaf(x1, wsF[h*INC + 64 + lane], s[h]);
      d[h] = fmaf(x1, wdF[h*INC + 64 + lane], d[h]);
    }
  }
  #pragma unroll
  for (int off = 32; off; off >>= 1){
    #pragma unroll
    for (int h = 0; h < 4; ++h){
      s[h] += __shfl_xor(s[h], off);
      d[h] += __shfl_xor(d[h], off);
    }
  }
  if (lane == 0){
    *(float4*)&aS[v*4] = make_float4(s[0], s[1], s[2], s[3]);
    *(float4*)&aD[v*4] = make_float4(d[0], d[1], d[2], d[3]);
  }
}

// ---------------- GAT prep: per-edge unnormalized exps + per-vertex self-f and 1/denom ----------------
__global__ __launch_bounds__(256) void k_gat_prep(
    const float* __restrict__ aS, const float* __restrict__ aD,
    const int* __restrict__ row_start, const int* __restrict__ csr,
    float4* __restrict__ alphaE, float4* __restrict__ fS4, float4* __restrict__ rin4){
  int v = blockIdx.x*4 + (threadIdx.x >> 6);
  int lane = threadIdx.x & 63;
  int s = row_start[v], e = row_start[v+1];

  float4 tD = *(const float4*)&aD[v*4];
  float ad0=tD.x, ad1=tD.y, ad2=tD.z, ad3=tD.w;
  float4 tS = *(const float4*)&aS[v*4];
  float ls0=lrelu02(tS.x+ad0), ls1=lrelu02(tS.y+ad1), ls2=lrelu02(tS.z+ad2), ls3=lrelu02(tS.w+ad3);

  float m0=ls0, m1=ls1, m2=ls2, m3=ls3;
  for (int i = s + lane; i < e; i += 64){
    int u = csr[i];
    float4 a4 = *(const float4*)&aS[u*4];
    m0 = fmaxf(m0, lrelu02(a4.x+ad0));
    m1 = fmaxf(m1, lrelu02(a4.y+ad1));
    m2 = fmaxf(m2, lrelu02(a4.z+ad2));
    m3 = fmaxf(m3, lrelu02(a4.w+ad3));
  }
  #pragma unroll
  for (int off = 32; off; off >>= 1){
    m0 = fmaxf(m0, __shfl_xor(m0, off));
    m1 = fmaxf(m1, __shfl_xor(m1, off));
    m2 = fmaxf(m2, __shfl_xor(m2, off));
    m3 = fmaxf(m3, __shfl_xor(m3, off));
  }

  float sd0=0.f, sd1=0.f, sd2=0.f, sd3=0.f;
  for (int i = s + lane; i < e; i += 64){
    int u = csr[i];
    float4 a4 = *(const float4*)&aS[u*4];
    float f0 = __expf(lrelu02(a4.x+ad0) - m0);
    float f1 = __expf(lrelu02(a4.y+ad1) - m1);
    float f2 = __expf(lrelu02(a4.z+ad2) - m2);
    float f3 = __expf(lrelu02(a4.w+ad3) - m3);
    sd0 += f0; sd1 += f1; sd2 += f2; sd3 += f3;
    alphaE[i] = make_float4(f0, f1, f2, f3);
  }
  #pragma unroll
  for (int off = 32; off; off >>= 1){
    sd0 += __shfl_xor(sd0, off);
    sd1 += __shfl_xor(sd1, off);
    sd2 += __shfl_xor(sd2, off);
    sd3 += __shfl_xor(sd3, off);
  }
  if (lane == 0){
    float es0=__expf(ls0-m0), es1=__expf(ls1-m1), es2=__expf(ls2-m2), es3=__expf(ls3-m3);
    fS4[v] = make_float4(es0, es1, es2, es3);
    rin4[v] = make_float4(1.f/(sd0+es0), 1.f/(sd1+es1), 1.f/(sd2+es2), 1.f/(sd3+es3));
  }
}

// ---------------- GAT aggregation v2: uniform record loads, frag-packs output ----------------
template<int INC>   // 128 (e3, out lda 512) or 64 (d3, out lda 256)
__global__ __launch_bounds__(256) void k_gat_agg2(
    const float* __restrict__ X, const int* __restrict__ csr,
    const float4* __restrict__ alphaE, const float4* __restrict__ fS4,
    const float4* __restrict__ rin4, const int* __restrict__ row_start,
    unsigned short* __restrict__ outp){
  int v = blockIdx.x*4 + (threadIdx.x >> 6);
  int lane = threadIdx.x & 63;
  int s = __builtin_amdgcn_readfirstlane(row_start[v]);
  int e = __builtin_amdgcn_readfirstlane(row_start[v+1]);
  const int c2 = lane*2;

  float2 acc0={0,0}, acc1={0,0}, acc2={0,0}, acc3={0,0};
  float ac0=0.f, ac1=0.f, ac2=0.f, ac3=0.f;

  int j = s;
  for (; j + 4 <= e; j += 4){
    int u0=csr[j], u1=csr[j+1], u2=csr[j+2], u3=csr[j+3];
    float4 f0=alphaE[j], f1=alphaE[j+1], f2=alphaE[j+2], f3=alphaE[j+3];
    if constexpr (INC == 128){
      float2 x0 = *(const float2*)&X[(size_t)u0*128 + c2];
      float2 x1 = *(const float2*)&X[(size_t)u1*128 + c2];
      float2 x2 = *(const float2*)&X[(size_t)u2*128 + c2];
      float2 x3 = *(const float2*)&X[(size_t)u3*128 + c2];
      acc0.x=fmaf(f0.x,x0.x,acc0.x); acc0.y=fmaf(f0.x,x0.y,acc0.y);
      acc1.x=fmaf(f0.y,x0.x,acc1.x); acc1.y=fmaf(f0.y,x0.y,acc1.y);
      acc2.x=fmaf(f0.z,x0.x,acc2.x); acc2.y=fmaf(f0.z,x0.y,acc2.y);
      acc3.x=fmaf(f0.w,x0.x,acc3.x); acc3.y=fmaf(f0.w,x0.y,acc3.y);
      acc0.x=fmaf(f1.x,x1.x,acc0.x); acc0.y=fmaf(f1.x,x1.y,acc0.y);
      acc1.x=fmaf(f1.y,x1.x,acc1.x); acc1.y=fmaf(f1.y,x1.y,acc1.y);
      acc2.x=fmaf(f1.z,x1.x,acc2.x); acc2.y=fmaf(f1.z,x1.y,acc2.y);
      acc3.x=fmaf(f1.w,x1.x,acc3.x); acc3.y=fmaf(f1.w,x1.y,acc3.y);
      acc0.x=fmaf(f2.x,x2.x,acc0.x); acc0.y=fmaf(f2.x,x2.y,acc0.y);
      acc1.x=fmaf(f2.y,x2.x,acc1.x); acc1.y=fmaf(f2.y,x2.y,acc1.y);
      acc2.x=fmaf(f2.z,x2.x,acc2.x); acc2.y=fmaf(f2.z,x2.y,acc2.y);
      acc3.x=fmaf(f2.w,x2.x,acc3.x); acc3.y=fmaf(f2.w,x2.y,acc3.y);
      acc0.x=fmaf(f3.x,x3.x,acc0.x); acc0.y=fmaf(f3.x,x3.y,acc0.y);
      acc1.x=fmaf(f3.y,x3.x,acc1.x); acc1.y=fmaf(f3.y,x3.y,acc1.y);
      acc2.x=fmaf(f3.z,x3.x,acc2.x); acc2.y=fmaf(f3.z,x3.y,acc2.y);
      acc3.x=fmaf(f3.w,x3.x,acc3.x); acc3.y=fmaf(f3.w,x3.y,acc3.y);
    } else {
      float x0 = X[(size_t)u0*64 + lane];
      float x1 = X[(size_t)u1*64 + lane];
      float x2 = X[(size_t)u2*64 + lane];
      float x3 = X[(size_t)u3*64 + lane];
      ac0=fmaf(f0.x,x0,ac0); ac1=fmaf(f0.y,x0,ac1); ac2=fmaf(f0.z,x0,ac2); ac3=fmaf(f0.w,x0,ac3);
      ac0=fmaf(f1.x,x1,ac0); ac1=fmaf(f1.y,x1,ac1); ac2=fmaf(f1.z,x1,ac2); ac3=fmaf(f1.w,x1,ac3);
      ac0=fmaf(f2.x,x2,ac0); ac1=fmaf(f2.y,x2,ac1); ac2=fmaf(f2.z,x2,ac2); ac3=fmaf(f2.w,x2,ac3);
      ac0=fmaf(f3.x,x3,ac0); ac1=fmaf(f3.y,x3,ac1); ac2=fmaf(f3.z,x3,ac2); ac3=fmaf(f3.w,x3,ac3);
    }
  }
  for (; j < e; ++j){
    int u = csr[j];
    float4 f = alphaE[j];
    if constexpr (INC == 128){
      float2 xu = *(const float2*)&X[(size_t)u*128 + c2];
      acc0.x=fmaf(f.x,xu.x,acc0.x); acc0.y=fmaf(f.x,xu.y,acc0.y);
      acc1.x=fmaf(f.y,xu.x,acc1.x); acc1.y=fmaf(f.y,xu.y,acc1.y);
      acc2.x=fmaf(f.z,xu.x,acc2.x); acc2.y=fmaf(f.z,xu.y,acc2.y);
      acc3.x=fmaf(f.w,xu.x,acc3.x); acc3.y=fmaf(f.w,xu.y,acc3.y);
    } else {
      float xu = X[(size_t)u*64 + lane];
      ac0=fmaf(f.x,xu,ac0); ac1=fmaf(f.y,xu,ac1); ac2=fmaf(f.z,xu,ac2); ac3=fmaf(f.w,xu,ac3);
    }
  }

  float4 fs = fS4[v];
  float4 rv = rin4[v];

  if constexpr (INC == 128){
    float2 xv = *(const float2*)&X[(size_t)v*128 + c2];
    const size_t loOff = (size_t)Npad*512;
    float ox, oy; unsigned short h0,l0,h1,l1;
    float fsx[4] = {fs.x, fs.y, fs.z, fs.w};
    float rvx[4] = {rv.x, rv.y, rv.z, rv.w};
    float2 accs[4] = {acc0, acc1, acc2, acc3};
    #pragma unroll
    for (int hh = 0; hh < 4; ++hh){
      ox=(accs[hh].x+fsx[hh]*xv.x)*rvx[hh]; oy=(accs[hh].y+fsx[hh]*xv.y)*rvx[hh];
      packhl(ox,h0,l0); packhl(oy,h1,l1);
      size_t a = fragaddr(v, hh*128 + c2, 512);
      *(unsigned int*)&outp[a] = (unsigned)h0|((unsigned)h1<<16);
      *(unsigned int*)&outp[a + loOff] = (unsigned)l0|((unsigned)l1<<16);
    }
  } else {
    float xv = X[(size_t)v*64 + lane];
    const size_t loOff = (size_t)Npad*256;
    float fsx[4] = {fs.x, fs.y, fs.z, fs.w};
    float rvx[4] = {rv.x, rv.y, rv.z, rv.w};
    float acx[4] = {ac0, ac1, ac2, ac3};
    #pragma unroll
    for (int hh = 0; hh < 4; ++hh){
      unsigned short hhh, lll;
      float o = (acx[hh]+fsx[hh]*xv)*rvx[hh];
      packhl(o,hhh,lll);
      size_t a = fragaddr(v, hh*64 + lane, 256);
      outp[a] = hhh; outp[a + loOff] = lll;
    }
  }
}

// ---------------- LDS-free MFMA GEMM, fragment-direct loads, fp16 hi/lo split ----------------
// out[n, z*Jh + j] = sum_k A[n, z*K + k] * W[k, z*Jh + j]
// A fragment-packed [Npad][lda] (lo at +Npad*lda); W fragment-packed (lo at +K*J).
// RW: row-groups per block (4/RW col-chunks). Block = 4 waves, each wave 16 rows x 64 cols.
// EPI: 0 = f32 raw; 1 = f32 relu(acc+bias); 2 = relu(acc+bias) then frag-pack (out lda J, lo +Npad*J)
template<int K, int J, int Jh, int RW, int EPI>
__global__ __launch_bounds__(256) void k_gemm(
    const unsigned short* __restrict__ Ap, int lda,
    const unsigned short* __restrict__ Wp,
    const float* __restrict__ bias,
    float* __restrict__ outf, unsigned short* __restrict__ outp){
  const int tid  = threadIdx.x;
  const int lane = tid & 63, w = tid >> 6;
  const int wr = w % RW, wc = w / RW;
  const int rowbase = blockIdx.x*(16*RW) + wr*16;
  const int colbase = blockIdx.z*Jh + blockIdx.y*(64*(4/RW)) + wc*64;
  const int akoff   = blockIdx.z*K;
  const size_t AloOff = (size_t)Npad*lda;
  const size_t WloOff = (size_t)K*J;
  const int l15 = lane & 15, lg = lane >> 4;

  const unsigned short* Abase =
      Ap + ((size_t)(rowbase>>4)*(lda>>3) + (akoff>>3) + lg)*128 + (size_t)l15*8;
  const int cfg0 = colbase >> 4;

  f32x4 accH[4] = {{0,0,0,0},{0,0,0,0},{0,0,0,0},{0,0,0,0}};
  f32x4 accM[4] = {{0,0,0,0},{0,0,0,0},{0,0,0,0},{0,0,0,0}};

  #pragma unroll 2
  for (int ks = 0; ks < K/32; ++ks){
    const unsigned short* ap = Abase + (size_t)ks*4*128;
    half8 aH = __builtin_bit_cast(half8, *(const uint4*)ap);
    half8 aL = __builtin_bit_cast(half8, *(const uint4*)(ap + AloOff));
    #pragma unroll
    for (int cf = 0; cf < 4; ++cf){
      const unsigned short* bp =
          Wp + ((size_t)(cfg0+cf)*(K/8) + ks*4 + lg)*128 + (size_t)l15*8;
      half8 bH = __builtin_bit_cast(half8, *(const uint4*)bp);
      half8 bL = __builtin_bit_cast(half8, *(const uint4*)(bp + WloOff));
      accH[cf] = __builtin_amdgcn_mfma_f32_16x16x32_f16(aH, bH, accH[cf], 0, 0, 0);
      accM[cf] = __builtin_amdgcn_mfma_f32_16x16x32_f16(aH, bL, accM[cf], 0, 0, 0);
      accM[cf] = __builtin_amdgcn_mfma_f32_16x16x32_f16(aL, bH, accM[cf], 0, 0, 0);
    }
  }

  // epilogue: C/D layout col = lane&15, row = (lane>>4)*4 + r
  #pragma unroll
  for (int cf = 0; cf < 4; ++cf){
    int col = colbase + cf*16 + l15;
    float bv = (EPI >= 1) ? bias[col] : 0.f;
    #pragma unroll
    for (int r = 0; r < 4; ++r){
      int row = rowbase + lg*4 + r;
      if (row < Nn){
        float v = accH[cf][r] + accM[cf][r]*(1.0f/2048.0f);
        if constexpr (EPI >= 1) v = fmaxf(v + bv, 0.f);
        if constexpr (EPI == 2){
          unsigned short hh, ll; packhl(v, hh, ll);
          size_t a = fragaddr(row, col, J);
          outp[a] = hh;
          outp[a + (size_t)Npad*J] = ll;
        } else {
          outf[(size_t)row*J + col] = v;
        }
      }
    }
  }
}

// ---------------- final 128 -> 4 matmul (+bias), one wave per row ----------------
__global__ __launch_bounds__(256) void k_mm_fin(
    const float* __restrict__ A, const float* __restrict__ W,
    const float* __restrict__ bias, float* __restrict__ out){
  int row = blockIdx.x*4 + (threadIdx.x >> 6);
  int lane = threadIdx.x & 63;
  float a0 = A[(size_t)row*128 + lane];
  float a1 = A[(size_t)row*128 + 64 + lane];
  float4 w0 = ((const float4*)W)[lane];
  float4 w1 = ((const float4*)W)[64 + lane];
  float p0 = fmaf(a1, w1.x, a0*w0.x);
  float p1 = fmaf(a1, w1.y, a0*w0.y);
  float p2 = fmaf(a1, w1.z, a0*w0.z);
  float p3 = fmaf(a1, w1.w, a0*w0.w);
  #pragma unroll
  for (int off = 32; off; off >>= 1){
    p0 += __shfl_xor(p0, off);
    p1 += __shfl_xor(p1, off);
    p2 += __shfl_xor(p2, off);
    p3 += __shfl_xor(p3, off);
  }
  if (lane == 0){
    float4 bv = *(const float4*)bias;
    *(float4*)&out[(size_t)row*4] = make_float4(p0+bv.x, p1+bv.y, p2+bv.z, p3+bv.w);
  }
}

// ---------------- launch ----------------
extern "C" void kernel_launch(void* const* d_in, const int* in_sizes, int n_in,
                              void* d_out, int out_size, void* d_ws, size_t ws_size,
                              hipStream_t stream){
  const float* x     = (const float*)d_in[0];
  const int*   ei    = (const int*)  d_in[1];
  const float* w_e1  = (const float*)d_in[2];
  const float* b_e1  = (const float*)d_in[3];
  const float* w_e2  = (const float*)d_in[4];
  const float* b_e2  = (const float*)d_in[5];
  const float* w_e3  = (const float*)d_in[6];
  const float* as_e3 = (const float*)d_in[7];
  const float* ad_e3 = (const float*)d_in[8];
  const float* b_e3  = (const float*)d_in[9];
  const float* w_d1  = (const float*)d_in[10];
  const float* b_d1  = (const float*)d_in[11];
  const float* w_d2  = (const float*)d_in[12];
  const float* b_d2  = (const float*)d_in[13];
  const float* w_d3  = (const float*)d_in[14];
  const float* as_d3 = (const float*)d_in[15];
  const float* ad_d3 = (const float*)d_in[16];
  const float* b_d3  = (const float*)d_in[17];
  const float* w_fc1 = (const float*)d_in[18];
  const float* b_fc1 = (const float*)d_in[19];
  const float* w_fc2 = (const float*)d_in[20];
  const float* b_fc2 = (const float*)d_in[21];
  const float* w_fin = (const float*)d_in[22];
  const float* b_fin = (const float*)d_in[23];

  char* ws = (char*)d_ws;
  size_t off = 0;
  auto alloc = [&](size_t bytes)->char*{
    char* p = ws + off;
    off += (bytes + 255) & ~size_t(255);
    return p;
  };
  int*   cnt       = (int*)  alloc((size_t)Nn*4);
  int*   fill      = (int*)  alloc((size_t)Nn*4);
  int*   row_start = (int*)  alloc((size_t)(Nn+1)*4);
  int*   csr       = (int*)  alloc((size_t)Ee*4);
  float* dinv      = (float*)alloc((size_t)Nn*4);
  int2*  erec      = (int2*) alloc((size_t)Ee*8);
  float4* alphaE   = (float4*)alloc((size_t)Ee*16);
  float4* fS4      = (float4*)alloc((size_t)Nn*16);
  float4* rin4     = (float4*)alloc((size_t)Nn*16);
  float* aSb       = (float*)alloc((size_t)Nn*16);
  float* aDb       = (float*)alloc((size_t)Nn*16);
  float* wsF_e3    = (float*)alloc(4*128*4);
  float* wdF_e3    = (float*)alloc(4*128*4);
  float* wsF_d3    = (float*)alloc(4*64*4);
  float* wdF_d3    = (float*)alloc(4*64*4);
  // fragment-packed weights (hi then lo)
  unsigned short* wp_e1  = (unsigned short*)alloc((size_t)32*64*4);
  unsigned short* wp_e2  = (unsigned short*)alloc((size_t)64*128*4);
  unsigned short* wp_e3  = (unsigned short*)alloc((size_t)128*512*4);
  unsigned short* wp_d1  = (unsigned short*)alloc((size_t)512*128*4);
  unsigned short* wp_d2  = (unsigned short*)alloc((size_t)128*64*4);
  unsigned short* wp_d3  = (unsigned short*)alloc((size_t)64*256*4);
  unsigned short* wp_fc1 = (unsigned short*)alloc((size_t)256*256*4);
  unsigned short* wp_fc2 = (unsigned short*)alloc((size_t)256*128*4);
  // activations (fragment-packed u16 hi/lo use Npad rows)
  unsigned short* P0 = (unsigned short*)alloc((size_t)Npad*32*4);
  float* X1 = (float*)alloc((size_t)Nn*64*4);
  float* X2 = (float*)alloc((size_t)Nn*128*4);
  unsigned short* S1 = (unsigned short*)alloc((size_t)Npad*512*4);
  unsigned short* S2 = (unsigned short*)alloc((size_t)Npad*512*4);
  char*  S3 = alloc((size_t)Npad*128*4);

  const int* srcp = ei;
  const int* dstp = ei + Ee;

  hipMemsetAsync(cnt, 0, (size_t)Nn*4, stream);
  hipMemsetAsync(fill, 0, (size_t)Nn*4, stream);
  k_count<<<(Ee+255)/256, 256, 0, stream>>>(dstp, cnt);
  k_scan<<<1, 1024, 0, stream>>>(cnt, row_start, dinv);
  k_scatter<<<(Ee+255)/256, 256, 0, stream>>>(srcp, dstp, row_start, fill, csr, dinv, erec);
  k_fold<128,128><<<1, 256, 0, stream>>>(w_e3, as_e3, ad_e3, wsF_e3, wdF_e3);
  k_fold<64,64><<<1, 256, 0, stream>>>(w_d3, as_d3, ad_d3, wsF_d3, wdF_d3);
  // fragment-pack weights
  k_packwf<32,64>  <<<  8, 256, 0, stream>>>(w_e1,  wp_e1);
  k_packwf<64,128> <<< 32, 256, 0, stream>>>(w_e2,  wp_e2);
  k_packwf<128,512><<<256, 256, 0, stream>>>(w_e3,  wp_e3);
  k_packwf<512,128><<<256, 256, 0, stream>>>(w_d1,  wp_d1);
  k_packwf<128,64> <<< 32, 256, 0, stream>>>(w_d2,  wp_d2);
  k_packwf<64,256> <<< 64, 256, 0, stream>>>(w_d3,  wp_d3);
  k_packwf<256,256><<<256, 256, 0, stream>>>(w_fc1, wp_fc1);
  k_packwf<256,128><<<128, 256, 0, stream>>>(w_fc2, wp_fc2);

  // encoder1: x1 = relu(agg(x) @ W1 + b1)
  k_gcn_agg<32,2><<<Nn/4, 256, 0, stream>>>(x, dinv, row_start, erec, nullptr, nullptr, nullptr, P0);
  k_gemm<32,64,64,4,1><<<dim3(313,1,1), 256, 0, stream>>>(P0, 32, wp_e1, b_e1, X1, nullptr);
  // encoder2: x2 = relu(agg(x1) @ W2 + b2)
  k_gcn_agg<64,2><<<Nn/4, 256, 0, stream>>>(X1, dinv, row_start, erec, nullptr, nullptr, nullptr, (unsigned short*)S3);
  k_gemm<64,128,128,2,1><<<dim3(626,1,1), 256, 0, stream>>>((unsigned short*)S3, 64, wp_e2, b_e2, X2, nullptr);
  // encoder3 (GAT): x3 = relu(headmm(gat_agg(x2)) + b3)
  k_attn_in<128><<<Nn/4, 256, 0, stream>>>(X2, wsF_e3, wdF_e3, aSb, aDb);
  k_gat_prep<<<Nn/4, 256, 0, stream>>>(aSb, aDb, row_start, csr, alphaE, fS4, rin4);
  k_gat_agg2<128><<<Nn/4, 256, 0, stream>>>(X2, csr, alphaE, fS4, rin4, row_start, S1);
  k_gemm<128,512,128,2,2><<<dim3(626,1,4), 256, 0, stream>>>(S1, 512, wp_e3, b_e3, nullptr, S2);
  // decoder1: h4 = relu(agg(x3 @ Wd1) + bd1) + x2
  k_gemm<512,128,128,2,0><<<dim3(626,1,1), 256, 0, stream>>>(S2, 512, wp_d1, nullptr, (float*)S3, nullptr);
  k_gcn_agg<128,3><<<Nn/4, 256, 0, stream>>>((float*)S3, dinv, row_start, erec, b_d1, X2, nullptr, S1);
  // decoder2: h5 = relu(agg(h4 @ Wd2) + bd2) + x1
  k_gemm<128,64,64,4,0><<<dim3(313,1,1), 256, 0, stream>>>(S1, 128, wp_d2, nullptr, (float*)S2, nullptr);
  k_gcn_agg<64,1><<<Nn/4, 256, 0, stream>>>((float*)S2, dinv, row_start, erec, b_d2, X1, (float*)S3, nullptr);
  // decoder3 (GAT): h6 = relu(headmm(gat_agg(h5)) + bd3)
  k_attn_in<64><<<Nn/4, 256, 0, stream>>>((float*)S3, wsF_d3, wdF_d3, aSb, aDb);
  k_gat_prep<<<Nn/4, 256, 0, stream>>>(aSb, aDb, row_start, csr, alphaE, fS4, rin4);
  k_gat_agg2<64><<<Nn/4, 256, 0, stream>>>((float*)S3, csr, alphaE, fS4, rin4, row_start, S1);
  k_gemm<64,256,64,4,2><<<dim3(313,1,4), 256, 0, stream>>>(S1, 256, wp_d3, b_d3, nullptr, S2);
  // MLP head
  k_gemm<256,256,256,2,2><<<dim3(626,2,1), 256, 0, stream>>>(S2, 256, wp_fc1, b_fc1, nullptr, S1);
  k_gemm<256,128,128,2,1><<<dim3(626,1,1), 256, 0, stream>>>(S1, 256, wp_fc2, b_fc2, (float*)S2, nullptr);
  k_mm_fin<<<Nn/4, 256, 0, stream>>>((float*)S2, w_fin, b_fin, (float*)d_out);
}

// Round 8
// 350.233 us; speedup vs baseline: 1.2398x; 1.2398x over previous
//
#include <hip/hip_runtime.h>
#include <cstdint>
#include <cstddef>

static constexpr int Nn = 20000;
static constexpr int Ee = 320000;

typedef _Float16 half8 __attribute__((ext_vector_type(8)));
typedef float f32x4 __attribute__((ext_vector_type(4)));

__device__ __forceinline__ float lrelu02(float x){ return fmaxf(x, 0.2f*x); }
__device__ __forceinline__ float af(int x){ return __int_as_float(x); }

// split v = hi + lo/2048, hi/lo fp16 (lo pre-scaled to stay in normal range)
__device__ __forceinline__ void packhl(float v, unsigned short& h, unsigned short& l){
  _Float16 hh = (_Float16)v;
  _Float16 ll = (_Float16)((v - (float)hh) * 2048.0f);
  h = __builtin_bit_cast(unsigned short, hh);
  l = __builtin_bit_cast(unsigned short, ll);
}

// ---------------- CSR build ----------------
__global__ void k_count(const int* __restrict__ dst, int* __restrict__ cnt){
  int e = blockIdx.x*256 + threadIdx.x;
  if (e < Ee) atomicAdd(&cnt[dst[e]], 1);
}

__global__ void k_scan(const int* __restrict__ cnt, int* __restrict__ row_start,
                       float* __restrict__ dinv){
  __shared__ int part[1024];
  int tid = threadIdx.x;
  const int PER = 20;
  int base = tid*PER;
  int s = 0;
  for (int i = 0; i < PER; ++i){ int idx = base+i; if (idx < Nn) s += cnt[idx]; }
  part[tid] = s; __syncthreads();
  for (int off = 1; off < 1024; off <<= 1){
    int v = (tid >= off) ? part[tid-off] : 0;
    __syncthreads();
    part[tid] += v;
    __syncthreads();
  }
  int run = (tid == 0) ? 0 : part[tid-1];
  for (int i = 0; i < PER; ++i){
    int idx = base+i;
    if (idx < Nn){
      row_start[idx] = run;
      int c = cnt[idx];
      run += c;
      dinv[idx] = rsqrtf((float)(c+1));
    }
  }
  if (tid == 1023) row_start[Nn] = run;
}

__global__ void k_scatter(const int* __restrict__ src, const int* __restrict__ dst,
                          const int* __restrict__ row_start, int* __restrict__ fill,
                          int* __restrict__ csr, const float* __restrict__ dinv,
                          int2* __restrict__ erec){
  int e = blockIdx.x*256 + threadIdx.x;
  if (e < Ee){
    int d = dst[e];
    int pos = row_start[d] + atomicAdd(&fill[d], 1);
    int u = src[e];
    csr[pos] = u;
    erec[pos] = make_int2(u, __float_as_int(dinv[u]));
  }
}

// ---------------- mega weight-prep: all hi/lo fragment packs + both attention folds ----------------
// fragment pack layout: pos = ((col>>4)*(K/8) + (k>>3))*16 + (col&15))*8 + (k&7); lo at +K*J
struct PrepArgs {
  const float *w_e1,*w_e2,*w_e3,*w_d1,*w_d2,*w_d3,*w_fc1,*w_fc2;
  unsigned short *p_e1,*p_e2,*p_e3,*p_d1,*p_d2,*p_d3,*p_fc1,*p_fc2;
  const float *as_e3,*ad_e3,*as_d3,*ad_d3;
  float *wsF_e3,*wdF_e3,*wsF_d3,*wdF_d3;
};

__device__ __forceinline__ void packw_one(const float* __restrict__ W,
                                          unsigned short* __restrict__ out,
                                          int i, int jlog, int K){
  int k = i >> jlog, col = i - (k << jlog);
  unsigned short h, l; packhl(W[i], h, l);
  size_t pos = ((size_t)((col>>4)*(K>>3) + (k>>3))*16 + (col&15))*8 + (k&7);
  out[pos] = h;
  out[pos + ((size_t)K << jlog)] = l;
}

__global__ void k_prep_weights(PrepArgs a){
  int i = blockIdx.x*256 + threadIdx.x;
  if      (i <   2048) packw_one(a.w_e1,  a.p_e1,  i,          6,  32);
  else if (i <  10240) packw_one(a.w_e2,  a.p_e2,  i-2048,     7,  64);
  else if (i <  75776) packw_one(a.w_e3,  a.p_e3,  i-10240,    9, 128);
  else if (i < 141312) packw_one(a.w_d1,  a.p_d1,  i-75776,    7, 512);
  else if (i < 149504) packw_one(a.w_d2,  a.p_d2,  i-141312,   6, 128);
  else if (i < 165888) packw_one(a.w_d3,  a.p_d3,  i-149504,   8,  64);
  else if (i < 231424) packw_one(a.w_fc1, a.p_fc1, i-165888,   8, 256);
  else if (i < 264192) packw_one(a.w_fc2, a.p_fc2, i-231424,   7, 256);
  else if (i < 264704){           // fold e3: INC=128, C=128
    int t = i - 264192;           // 0..511
    int h = t >> 7, k = t & 127;
    float s = 0.f, d = 0.f;
    #pragma unroll 4
    for (int c = 0; c < 128; ++c){
      float wv = a.w_e3[(size_t)k*512 + h*128 + c];
      s = fmaf(wv, a.as_e3[h*128 + c], s);
      d = fmaf(wv, a.ad_e3[h*128 + c], d);
    }
    a.wsF_e3[h*128 + k] = s;
    a.wdF_e3[h*128 + k] = d;
  } else if (i < 264960){         // fold d3: INC=64, C=64
    int t = i - 264704;           // 0..255
    int h = t >> 6, k = t & 63;
    float s = 0.f, d = 0.f;
    #pragma unroll 4
    for (int c = 0; c < 64; ++c){
      float wv = a.w_d3[(size_t)k*256 + h*64 + c];
      s = fmaf(wv, a.as_d3[h*64 + c], s);
      d = fmaf(wv, a.ad_d3[h*64 + c], d);
    }
    a.wsF_d3[h*64 + k] = s;
    a.wdF_d3[h*64 + k] = d;
  }
}

// ---------------- GCN aggregation (uniform record loads) ----------------
// POST: 0 = f32 raw; 1 = f32 relu(+bias)+skip; 2 = pack raw; 3 = relu+bias+skip then pack
template<int C, int POST>
__global__ __launch_bounds__(256) void k_gcn_agg(
    const float* __restrict__ h, const float* __restrict__ dinv,
    const int* __restrict__ row_start, const int2* __restrict__ erec,
    const float* __restrict__ bias, const float* __restrict__ skip,
    float* __restrict__ outf, unsigned short* __restrict__ outp){
  int v = blockIdx.x*4 + (threadIdx.x >> 6);
  int lane = threadIdx.x & 63;
  int s = __builtin_amdgcn_readfirstlane(row_start[v]);
  int e = __builtin_amdgcn_readfirstlane(row_start[v+1]);
  float dv = dinv[v];
  const int c = (C==32) ? (lane & 31) : ((C==128) ? lane*2 : lane);

  float a0 = 0.f, a1 = 0.f;
  if constexpr (C == 32){
    int half = lane >> 5;
    int j = s + half;
    for (; j + 2 < e; j += 4){
      int2 r0 = erec[j], r1 = erec[j+2];
      float t0 = h[(size_t)r0.x*32 + c];
      float t1 = h[(size_t)r1.x*32 + c];
      a0 = fmaf(af(r0.y), t0, a0);
      a0 = fmaf(af(r1.y), t1, a0);
    }
    if (j < e){
      int2 r0 = erec[j];
      a0 = fmaf(af(r0.y), h[(size_t)r0.x*32 + c], a0);
    }
    a0 += __shfl_xor(a0, 32);
  } else if constexpr (C == 128){
    int j = s;
    for (; j + 4 <= e; j += 4){
      int2 r0 = erec[j], r1 = erec[j+1], r2 = erec[j+2], r3 = erec[j+3];
      float2 t0 = *(const float2*)&h[(size_t)r0.x*128 + c];
      float2 t1 = *(const float2*)&h[(size_t)r1.x*128 + c];
      float2 t2 = *(const float2*)&h[(size_t)r2.x*128 + c];
      float2 t3 = *(const float2*)&h[(size_t)r3.x*128 + c];
      a0=fmaf(af(r0.y),t0.x,a0); a1=fmaf(af(r0.y),t0.y,a1);
      a0=fmaf(af(r1.y),t1.x,a0); a1=fmaf(af(r1.y),t1.y,a1);
      a0=fmaf(af(r2.y),t2.x,a0); a1=fmaf(af(r2.y),t2.y,a1);
      a0=fmaf(af(r3.y),t3.x,a0); a1=fmaf(af(r3.y),t3.y,a1);
    }
    for (; j < e; ++j){
      int2 r = erec[j];
      float2 t = *(const float2*)&h[(size_t)r.x*128 + c];
      a0 = fmaf(af(r.y), t.x, a0); a1 = fmaf(af(r.y), t.y, a1);
    }
  } else { // C == 64
    int j = s;
    for (; j + 4 <= e; j += 4){
      int2 r0 = erec[j], r1 = erec[j+1], r2 = erec[j+2], r3 = erec[j+3];
      float t0 = h[(size_t)r0.x*64 + c];
      float t1 = h[(size_t)r1.x*64 + c];
      float t2 = h[(size_t)r2.x*64 + c];
      float t3 = h[(size_t)r3.x*64 + c];
      a0=fmaf(af(r0.y),t0,a0); a0=fmaf(af(r1.y),t1,a0);
      a0=fmaf(af(r2.y),t2,a0); a0=fmaf(af(r3.y),t3,a0);
    }
    for (; j < e; ++j){
      int2 r = erec[j];
      a0 = fmaf(af(r.y), h[(size_t)r.x*64 + c], a0);
    }
  }

  if constexpr (C == 128){
    float2 hv = *(const float2*)&h[(size_t)v*128 + c];
    float vx = fmaf(a0, dv, hv.x*dv*dv);
    float vy = fmaf(a1, dv, hv.y*dv*dv);
    if constexpr (POST & 1){
      float2 bv = *(const float2*)&bias[c];
      float2 sk = *(const float2*)&skip[(size_t)v*128 + c];
      vx = fmaxf(vx + bv.x, 0.f) + sk.x;
      vy = fmaxf(vy + bv.y, 0.f) + sk.y;
    }
    if constexpr (POST & 2){
      unsigned short h0,l0,h1,l1; packhl(vx,h0,l0); packhl(vy,h1,l1);
      *(unsigned int*)&outp[(size_t)v*128 + c] = (unsigned)h0 | ((unsigned)h1<<16);
      *(unsigned int*)&outp[(size_t)v*128 + c + (size_t)Nn*128] = (unsigned)l0 | ((unsigned)l1<<16);
    } else {
      *(float2*)&outf[(size_t)v*128 + c] = make_float2(vx, vy);
    }
  } else if constexpr (C == 64){
    float val = fmaf(a0, dv, h[(size_t)v*64 + c]*dv*dv);
    if constexpr (POST & 1){
      val = fmaxf(val + bias[c], 0.f) + skip[(size_t)v*64 + c];
    }
    if constexpr (POST & 2){
      unsigned short hh,ll; packhl(val,hh,ll);
      outp[(size_t)v*64 + c] = hh;
      outp[(size_t)v*64 + c + (size_t)Nn*64] = ll;
    } else {
      outf[(size_t)v*64 + c] = val;
    }
  } else { // C == 32, pack only
    float val = fmaf(a0, dv, h[(size_t)v*32 + c]*dv*dv);
    if (lane < 32){
      unsigned short hh,ll; packhl(val,hh,ll);
      outp[(size_t)v*32 + c] = hh;
      outp[(size_t)v*32 + c + (size_t)Nn*32] = ll;
    }
  }
}

// ---------------- attention coefficients from the INPUT ----------------
template<int INC>
__global__ __launch_bounds__(256) void k_attn_in(
    const float* __restrict__ X, const float* __restrict__ wsF, const float* __restrict__ wdF,
    float* __restrict__ aS, float* __restrict__ aD){
  int v = blockIdx.x*4 + (threadIdx.x >> 6);
  int lane = threadIdx.x & 63;
  float x0 = X[(size_t)v*INC + lane];
  float x1 = (INC == 128) ? X[(size_t)v*INC + 64 + lane] : 0.f;
  float s[4], d[4];
  #pragma unroll
  for (int h = 0; h < 4; ++h){
    s[h] = x0*wsF[h*INC + lane];
    d[h] = x0*wdF[h*INC + lane];
    if constexpr (INC == 128){
      s[h] = fmaf(x1, wsF[h*INC + 64 + lane], s[h]);
      d[h] = fmaf(x1, wdF[h*INC + 64 + lane], d[h]);
    }
  }
  #pragma unroll
  for (int off = 32; off; off >>= 1){
    #pragma unroll
    for (int h = 0; h < 4; ++h){
      s[h] += __shfl_xor(s[h], off);
      d[h] += __shfl_xor(d[h], off);
    }
  }
  if (lane == 0){
    *(float4*)&aS[v*4] = make_float4(s[0], s[1], s[2], s[3]);
    *(float4*)&aD[v*4] = make_float4(d[0], d[1], d[2], d[3]);
  }
}

// ---------------- GAT prep, single pass (no max-shift: logits are O(1), exp safe) ----------------
__global__ __launch_bounds__(256) void k_gat_prep(
    const float* __restrict__ aS, const float* __restrict__ aD,
    const int* __restrict__ row_start, const int* __restrict__ csr,
    float4* __restrict__ alphaE, float4* __restrict__ fS4, float4* __restrict__ rin4){
  int v = blockIdx.x*4 + (threadIdx.x >> 6);
  int lane = threadIdx.x & 63;
  int s = row_start[v], e = row_start[v+1];

  float4 tD = *(const float4*)&aD[v*4];
  float ad0=tD.x, ad1=tD.y, ad2=tD.z, ad3=tD.w;
  float4 tS = *(const float4*)&aS[v*4];

  float sd0=0.f, sd1=0.f, sd2=0.f, sd3=0.f;
  for (int i = s + lane; i < e; i += 64){
    int u = csr[i];
    float4 a4 = *(const float4*)&aS[u*4];
    float f0 = __expf(lrelu02(a4.x+ad0));
    float f1 = __expf(lrelu02(a4.y+ad1));
    float f2 = __expf(lrelu02(a4.z+ad2));
    float f3 = __expf(lrelu02(a4.w+ad3));
    sd0 += f0; sd1 += f1; sd2 += f2; sd3 += f3;
    alphaE[i] = make_float4(f0, f1, f2, f3);
  }
  #pragma unroll
  for (int off = 32; off; off >>= 1){
    sd0 += __shfl_xor(sd0, off);
    sd1 += __shfl_xor(sd1, off);
    sd2 += __shfl_xor(sd2, off);
    sd3 += __shfl_xor(sd3, off);
  }
  if (lane == 0){
    float es0=__expf(lrelu02(tS.x+ad0)), es1=__expf(lrelu02(tS.y+ad1));
    float es2=__expf(lrelu02(tS.z+ad2)), es3=__expf(lrelu02(tS.w+ad3));
    fS4[v] = make_float4(es0, es1, es2, es3);
    rin4[v] = make_float4(1.f/(sd0+es0), 1.f/(sd1+es1), 1.f/(sd2+es2), 1.f/(sd3+es3));
  }
}

// ---------------- GAT aggregation v2: uniform record loads, packs output ----------------
template<int INC>   // 128 (e3) or 64 (d3)
__global__ __launch_bounds__(256) void k_gat_agg2(
    const float* __restrict__ X, const int* __restrict__ csr,
    const float4* __restrict__ alphaE, const float4* __restrict__ fS4,
    const float4* __restrict__ rin4, const int* __restrict__ row_start,
    unsigned short* __restrict__ outp){
  int v = blockIdx.x*4 + (threadIdx.x >> 6);
  int lane = threadIdx.x & 63;
  int s = __builtin_amdgcn_readfirstlane(row_start[v]);
  int e = __builtin_amdgcn_readfirstlane(row_start[v+1]);
  const int c2 = lane*2;

  float2 acc0={0,0}, acc1={0,0}, acc2={0,0}, acc3={0,0};
  float ac0=0.f, ac1=0.f, ac2=0.f, ac3=0.f;

  int j = s;
  for (; j + 4 <= e; j += 4){
    int u0=csr[j], u1=csr[j+1], u2=csr[j+2], u3=csr[j+3];
    float4 f0=alphaE[j], f1=alphaE[j+1], f2=alphaE[j+2], f3=alphaE[j+3];
    if constexpr (INC == 128){
      float2 x0 = *(const float2*)&X[(size_t)u0*128 + c2];
      float2 x1 = *(const float2*)&X[(size_t)u1*128 + c2];
      float2 x2 = *(const float2*)&X[(size_t)u2*128 + c2];
      float2 x3 = *(const float2*)&X[(size_t)u3*128 + c2];
      acc0.x=fmaf(f0.x,x0.x,acc0.x); acc0.y=fmaf(f0.x,x0.y,acc0.y);
      acc1.x=fmaf(f0.y,x0.x,acc1.x); acc1.y=fmaf(f0.y,x0.y,acc1.y);
      acc2.x=fmaf(f0.z,x0.x,acc2.x); acc2.y=fmaf(f0.z,x0.y,acc2.y);
      acc3.x=fmaf(f0.w,x0.x,acc3.x); acc3.y=fmaf(f0.w,x0.y,acc3.y);
      acc0.x=fmaf(f1.x,x1.x,acc0.x); acc0.y=fmaf(f1.x,x1.y,acc0.y);
      acc1.x=fmaf(f1.y,x1.x,acc1.x); acc1.y=fmaf(f1.y,x1.y,acc1.y);
      acc2.x=fmaf(f1.z,x1.x,acc2.x); acc2.y=fmaf(f1.z,x1.y,acc2.y);
      acc3.x=fmaf(f1.w,x1.x,acc3.x); acc3.y=fmaf(f1.w,x1.y,acc3.y);
      acc0.x=fmaf(f2.x,x2.x,acc0.x); acc0.y=fmaf(f2.x,x2.y,acc0.y);
      acc1.x=fmaf(f2.y,x2.x,acc1.x); acc1.y=fmaf(f2.y,x2.y,acc1.y);
      acc2.x=fmaf(f2.z,x2.x,acc2.x); acc2.y=fmaf(f2.z,x2.y,acc2.y);
      acc3.x=fmaf(f2.w,x2.x,acc3.x); acc3.y=fmaf(f2.w,x2.y,acc3.y);
      acc0.x=fmaf(f3.x,x3.x,acc0.x); acc0.y=fmaf(f3.x,x3.y,acc0.y);
      acc1.x=fmaf(f3.y,x3.x,acc1.x); acc1.y=fmaf(f3.y,x3.y,acc1.y);
      acc2.x=fmaf(f3.z,x3.x,acc2.x); acc2.y=fmaf(f3.z,x3.y,acc2.y);
      acc3.x=fmaf(f3.w,x3.x,acc3.x); acc3.y=fmaf(f3.w,x3.y,acc3.y);
    } else {
      float x0 = X[(size_t)u0*64 + lane];
      float x1 = X[(size_t)u1*64 + lane];
      float x2 = X[(size_t)u2*64 + lane];
      float x3 = X[(size_t)u3*64 + lane];
      ac0=fmaf(f0.x,x0,ac0); ac1=fmaf(f0.y,x0,ac1); ac2=fmaf(f0.z,x0,ac2); ac3=fmaf(f0.w,x0,ac3);
      ac0=fmaf(f1.x,x1,ac0); ac1=fmaf(f1.y,x1,ac1); ac2=fmaf(f1.z,x1,ac2); ac3=fmaf(f1.w,x1,ac3);
      ac0=fmaf(f2.x,x2,ac0); ac1=fmaf(f2.y,x2,ac1); ac2=fmaf(f2.z,x2,ac2); ac3=fmaf(f2.w,x2,ac3);
      ac0=fmaf(f3.x,x3,ac0); ac1=fmaf(f3.y,x3,ac1); ac2=fmaf(f3.z,x3,ac2); ac3=fmaf(f3.w,x3,ac3);
    }
  }
  for (; j < e; ++j){
    int u = csr[j];
    float4 f = alphaE[j];
    if constexpr (INC == 128){
      float2 xu = *(const float2*)&X[(size_t)u*128 + c2];
      acc0.x=fmaf(f.x,xu.x,acc0.x); acc0.y=fmaf(f.x,xu.y,acc0.y);
      acc1.x=fmaf(f.y,xu.x,acc1.x); acc1.y=fmaf(f.y,xu.y,acc1.y);
      acc2.x=fmaf(f.z,xu.x,acc2.x); acc2.y=fmaf(f.z,xu.y,acc2.y);
      acc3.x=fmaf(f.w,xu.x,acc3.x); acc3.y=fmaf(f.w,xu.y,acc3.y);
    } else {
      float xu = X[(size_t)u*64 + lane];
      ac0=fmaf(f.x,xu,ac0); ac1=fmaf(f.y,xu,ac1); ac2=fmaf(f.z,xu,ac2); ac3=fmaf(f.w,xu,ac3);
    }
  }

  float4 fs = fS4[v];
  float4 rv = rin4[v];

  if constexpr (INC == 128){
    float2 xv = *(const float2*)&X[(size_t)v*128 + c2];
    const size_t loOff = (size_t)Nn*512;
    float ox, oy; unsigned short h0,l0,h1,l1;
    ox=(acc0.x+fs.x*xv.x)*rv.x; oy=(acc0.y+fs.x*xv.y)*rv.x;
    packhl(ox,h0,l0); packhl(oy,h1,l1);
    *(unsigned int*)&outp[(size_t)v*512 +   0 + c2] = (unsigned)h0|((unsigned)h1<<16);
    *(unsigned int*)&outp[(size_t)v*512 +   0 + c2 + loOff] = (unsigned)l0|((unsigned)l1<<16);
    ox=(acc1.x+fs.y*xv.x)*rv.y; oy=(acc1.y+fs.y*xv.y)*rv.y;
    packhl(ox,h0,l0); packhl(oy,h1,l1);
    *(unsigned int*)&outp[(size_t)v*512 + 128 + c2] = (unsigned)h0|((unsigned)h1<<16);
    *(unsigned int*)&outp[(size_t)v*512 + 128 + c2 + loOff] = (unsigned)l0|((unsigned)l1<<16);
    ox=(acc2.x+fs.z*xv.x)*rv.z; oy=(acc2.y+fs.z*xv.y)*rv.z;
    packhl(ox,h0,l0); packhl(oy,h1,l1);
    *(unsigned int*)&outp[(size_t)v*512 + 256 + c2] = (unsigned)h0|((unsigned)h1<<16);
    *(unsigned int*)&outp[(size_t)v*512 + 256 + c2 + loOff] = (unsigned)l0|((unsigned)l1<<16);
    ox=(acc3.x+fs.w*xv.x)*rv.w; oy=(acc3.y+fs.w*xv.y)*rv.w;
    packhl(ox,h0,l0); packhl(oy,h1,l1);
    *(unsigned int*)&outp[(size_t)v*512 + 384 + c2] = (unsigned)h0|((unsigned)h1<<16);
    *(unsigned int*)&outp[(size_t)v*512 + 384 + c2 + loOff] = (unsigned)l0|((unsigned)l1<<16);
  } else {
    float xv = X[(size_t)v*64 + lane];
    const size_t loOff = (size_t)Nn*256;
    unsigned short hh,ll;
    float o;
    o = (ac0+fs.x*xv)*rv.x; packhl(o,hh,ll);
    outp[(size_t)v*256 +   0 + lane] = hh; outp[(size_t)v*256 +   0 + lane + loOff] = ll;
    o = (ac1+fs.y*xv)*rv.y; packhl(o,hh,ll);
    outp[(size_t)v*256 +  64 + lane] = hh; outp[(size_t)v*256 +  64 + lane + loOff] = ll;
    o = (ac2+fs.z*xv)*rv.z; packhl(o,hh,ll);
    outp[(size_t)v*256 + 128 + lane] = hh; outp[(size_t)v*256 + 128 + lane + loOff] = ll;
    o = (ac3+fs.w*xv)*rv.w; packhl(o,hh,ll);
    outp[(size_t)v*256 + 192 + lane] = hh; outp[(size_t)v*256 + 192 + lane + loOff] = ll;
  }
}

// ---------------- MFMA GEMM, fp16 hi/lo split, LDS-staged, fragment-packed W ----------------
// out[n, z*Jh + j] = sum_k A[n, z*K + k] * W[k, z*Jh + j]
// A packed: hi u16 [Nn][lda], lo at +Nn*lda.  W fragment-packed (k_prep_weights), lo at +K*J.
// EPI: 0 = f32 raw; 1 = f32 relu(acc+bias); 2 = relu(acc+bias) then pack (lo at +Nn*J)
template<int K, int J, int Jh, int EPI>
__global__ __launch_bounds__(256) void k_gemm(
    const unsigned short* __restrict__ Ahi, int lda,
    const unsigned short* __restrict__ Wp,
    const float* __restrict__ bias,
    float* __restrict__ outf, unsigned short* __restrict__ outp){
  __shared__ unsigned short sAhi[2*64*8], sAlo[2*64*8];
  __shared__ unsigned short sBhi[4*64*8], sBlo[4*64*8];

  const int tid  = threadIdx.x;
  const int lane = tid & 63, w = tid >> 6;
  const int rh = w & 1, ch = w >> 1;
  const int rb = blockIdx.x;
  const int colbase = blockIdx.z*Jh + blockIdx.y*64;
  const int akoff   = blockIdx.z*K;
  const size_t AloOff = (size_t)Nn*lda;
  const size_t WloOff = (size_t)K*J;

  f32x4 accH0 = {0,0,0,0}, accH1 = {0,0,0,0};
  f32x4 accM0 = {0,0,0,0}, accM1 = {0,0,0,0};

  // A staging map
  const int arow = tid >> 3;
  const int ak4  = (tid & 7) * 4;
  const int aw_idx = (((arow>>4)*4 + (ak4>>3))*16 + (arow&15))*8 + (ak4&4);
  const unsigned short* Ag = Ahi + (size_t)(rb*32 + arow)*lda + akoff + ak4;
  // B staging map (fragment-packed W): one uint4 per buffer per k-step
  const int bcol = tid & 63;
  const int bkg  = tid >> 6;
  const int bw_idx = (((bcol>>4)*4 + bkg)*16 + (bcol&15))*8;
  const int cf_g  = (colbase>>4) + (bcol>>4);
  const size_t wbase = ((size_t)cf_g*(K/8)*16 + (size_t)(bcol&15))*8;

  #pragma unroll 1
  for (int ks = 0; ks < K/32; ++ks){
    if (ks) __syncthreads();
    { // stage A
      const unsigned short* p = Ag + ks*32;
      uint2 hv = *(const uint2*)p;
      uint2 lv = *(const uint2*)(p + AloOff);
      *(uint2*)&sAhi[aw_idx] = hv;
      *(uint2*)&sAlo[aw_idx] = lv;
    }
    { // stage B (coalesced uint4 from fragment-packed W)
      size_t goff = wbase + (size_t)(ks*4 + bkg)*16*8;
      uint4 hv = *(const uint4*)&Wp[goff];
      uint4 lv = *(const uint4*)&Wp[goff + WloOff];
      *(uint4*)&sBhi[bw_idx] = hv;
      *(uint4*)&sBlo[bw_idx] = lv;
    }
    __syncthreads();

    half8 aH = *(const half8*)&sAhi[(rh*64 + lane)*8];
    half8 aL = *(const half8*)&sAlo[(rh*64 + lane)*8];
    {
      int cf = ch*2;
      half8 bH = *(const half8*)&sBhi[(cf*64 + lane)*8];
      half8 bL = *(const half8*)&sBlo[(cf*64 + lane)*8];
      accH0 = __builtin_amdgcn_mfma_f32_16x16x32_f16(aH, bH, accH0, 0, 0, 0);
      accM0 = __builtin_amdgcn_mfma_f32_16x16x32_f16(aH, bL, accM0, 0, 0, 0);
      accM0 = __builtin_amdgcn_mfma_f32_16x16x32_f16(aL, bH, accM0, 0, 0, 0);
    }
    {
      int cf = ch*2 + 1;
      half8 bH = *(const half8*)&sBhi[(cf*64 + lane)*8];
      half8 bL = *(const half8*)&sBlo[(cf*64 + lane)*8];
      accH1 = __builtin_amdgcn_mfma_f32_16x16x32_f16(aH, bH, accH1, 0, 0, 0);
      accM1 = __builtin_amdgcn_mfma_f32_16x16x32_f16(aH, bL, accM1, 0, 0, 0);
      accM1 = __builtin_amdgcn_mfma_f32_16x16x32_f16(aL, bH, accM1, 0, 0, 0);
    }
  }

  // epilogue: C/D layout col = lane&15, row = (lane>>4)*4 + r
  #pragma unroll
  for (int q = 0; q < 2; ++q){
    int cf = ch*2 + q;
    int col = colbase + cf*16 + (lane & 15);
    float bv = (EPI >= 1) ? bias[col] : 0.f;
    const f32x4& aH = q ? accH1 : accH0;
    const f32x4& aM = q ? accM1 : accM0;
    #pragma unroll
    for (int r = 0; r < 4; ++r){
      int row = rb*32 + rh*16 + ((lane>>4)*4 + r);
      float v = aH[r] + aM[r]*(1.0f/2048.0f);
      if constexpr (EPI >= 1) v = fmaxf(v + bv, 0.f);
      if constexpr (EPI == 2){
        unsigned short hh, ll; packhl(v, hh, ll);
        outp[(size_t)row*J + col] = hh;
        outp[(size_t)row*J + col + (size_t)Nn*J] = ll;
      } else {
        outf[(size_t)row*J + col] = v;
      }
    }
  }
}

// ---------------- final 128 -> 4 matmul (+bias), one wave per row ----------------
__global__ __launch_bounds__(256) void k_mm_fin(
    const float* __restrict__ A, const float* __restrict__ W,
    const float* __restrict__ bias, float* __restrict__ out){
  int row = blockIdx.x*4 + (threadIdx.x >> 6);
  int lane = threadIdx.x & 63;
  float a0 = A[(size_t)row*128 + lane];
  float a1 = A[(size_t)row*128 + 64 + lane];
  float4 w0 = ((const float4*)W)[lane];
  float4 w1 = ((const float4*)W)[64 + lane];
  float p0 = fmaf(a1, w1.x, a0*w0.x);
  float p1 = fmaf(a1, w1.y, a0*w0.y);
  float p2 = fmaf(a1, w1.z, a0*w0.z);
  float p3 = fmaf(a1, w1.w, a0*w0.w);
  #pragma unroll
  for (int off = 32; off; off >>= 1){
    p0 += __shfl_xor(p0, off);
    p1 += __shfl_xor(p1, off);
    p2 += __shfl_xor(p2, off);
    p3 += __shfl_xor(p3, off);
  }
  if (lane == 0){
    float4 bv = *(const float4*)bias;
    *(float4*)&out[(size_t)row*4] = make_float4(p0+bv.x, p1+bv.y, p2+bv.z, p3+bv.w);
  }
}

// ---------------- launch ----------------
extern "C" void kernel_launch(void* const* d_in, const int* in_sizes, int n_in,
                              void* d_out, int out_size, void* d_ws, size_t ws_size,
                              hipStream_t stream){
  const float* x     = (const float*)d_in[0];
  const int*   ei    = (const int*)  d_in[1];
  const float* w_e1  = (const float*)d_in[2];
  const float* b_e1  = (const float*)d_in[3];
  const float* w_e2  = (const float*)d_in[4];
  const float* b_e2  = (const float*)d_in[5];
  const float* w_e3  = (const float*)d_in[6];
  const float* as_e3 = (const float*)d_in[7];
  const float* ad_e3 = (const float*)d_in[8];
  const float* b_e3  = (const float*)d_in[9];
  const float* w_d1  = (const float*)d_in[10];
  const float* b_d1  = (const float*)d_in[11];
  const float* w_d2  = (const float*)d_in[12];
  const float* b_d2  = (const float*)d_in[13];
  const float* w_d3  = (const float*)d_in[14];
  const float* as_d3 = (const float*)d_in[15];
  const float* ad_d3 = (const float*)d_in[16];
  const float* b_d3  = (const float*)d_in[17];
  const float* w_fc1 = (const float*)d_in[18];
  const float* b_fc1 = (const float*)d_in[19];
  const float* w_fc2 = (const float*)d_in[20];
  const float* b_fc2 = (const float*)d_in[21];
  const float* w_fin = (const float*)d_in[22];
  const float* b_fin = (const float*)d_in[23];

  char* ws = (char*)d_ws;
  size_t off = 0;
  auto alloc = [&](size_t bytes)->char*{
    char* p = ws + off;
    off += (bytes + 255) & ~size_t(255);
    return p;
  };
  int*   cnt       = (int*)  alloc((size_t)Nn*4);      // cnt+fill contiguous: one memset
  int*   fill      = (int*)  alloc((size_t)Nn*4);
  int*   row_start = (int*)  alloc((size_t)(Nn+1)*4);
  int*   csr       = (int*)  alloc((size_t)Ee*4);
  float* dinv      = (float*)alloc((size_t)Nn*4);
  int2*  erec      = (int2*) alloc((size_t)Ee*8);
  float4* alphaE   = (float4*)alloc((size_t)Ee*16);
  float4* fS4      = (float4*)alloc((size_t)Nn*16);
  float4* rin4     = (float4*)alloc((size_t)Nn*16);
  float* aSb       = (float*)alloc((size_t)Nn*16);
  float* aDb       = (float*)alloc((size_t)Nn*16);
  float* wsF_e3    = (float*)alloc(4*128*4);
  float* wdF_e3    = (float*)alloc(4*128*4);
  float* wsF_d3    = (float*)alloc(4*64*4);
  float* wdF_d3    = (float*)alloc(4*64*4);
  // fragment-packed weights (hi then lo)
  unsigned short* wp_e1  = (unsigned short*)alloc((size_t)32*64*4);
  unsigned short* wp_e2  = (unsigned short*)alloc((size_t)64*128*4);
  unsigned short* wp_e3  = (unsigned short*)alloc((size_t)128*512*4);
  unsigned short* wp_d1  = (unsigned short*)alloc((size_t)512*128*4);
  unsigned short* wp_d2  = (unsigned short*)alloc((size_t)128*64*4);
  unsigned short* wp_d3  = (unsigned short*)alloc((size_t)64*256*4);
  unsigned short* wp_fc1 = (unsigned short*)alloc((size_t)256*256*4);
  unsigned short* wp_fc2 = (unsigned short*)alloc((size_t)256*128*4);
  // activations
  unsigned short* P0 = (unsigned short*)alloc((size_t)Nn*32*4);
  float* X1 = (float*)alloc((size_t)Nn*64*4);
  float* X2 = (float*)alloc((size_t)Nn*128*4);
  unsigned short* S1 = (unsigned short*)alloc((size_t)Nn*512*4);
  unsigned short* S2 = (unsigned short*)alloc((size_t)Nn*512*4);
  char*  S3 = alloc((size_t)Nn*128*4);

  const int* srcp = ei;
  const int* dstp = ei + Ee;

  hipMemsetAsync(cnt, 0, (size_t)(((size_t)Nn*4 + 255) & ~size_t(255)) + (size_t)Nn*4, stream);

  PrepArgs pa;
  pa.w_e1=w_e1; pa.w_e2=w_e2; pa.w_e3=w_e3; pa.w_d1=w_d1;
  pa.w_d2=w_d2; pa.w_d3=w_d3; pa.w_fc1=w_fc1; pa.w_fc2=w_fc2;
  pa.p_e1=wp_e1; pa.p_e2=wp_e2; pa.p_e3=wp_e3; pa.p_d1=wp_d1;
  pa.p_d2=wp_d2; pa.p_d3=wp_d3; pa.p_fc1=wp_fc1; pa.p_fc2=wp_fc2;
  pa.as_e3=as_e3; pa.ad_e3=ad_e3; pa.as_d3=as_d3; pa.ad_d3=ad_d3;
  pa.wsF_e3=wsF_e3; pa.wdF_e3=wdF_e3; pa.wsF_d3=wsF_d3; pa.wdF_d3=wdF_d3;
  k_prep_weights<<<1035, 256, 0, stream>>>(pa);

  k_count<<<(Ee+255)/256, 256, 0, stream>>>(dstp, cnt);
  k_scan<<<1, 1024, 0, stream>>>(cnt, row_start, dinv);
  k_scatter<<<(Ee+255)/256, 256, 0, stream>>>(srcp, dstp, row_start, fill, csr, dinv, erec);

  // encoder1: x1 = relu(agg(x) @ W1 + b1)
  k_gcn_agg<32,2><<<Nn/4, 256, 0, stream>>>(x, dinv, row_start, erec, nullptr, nullptr, nullptr, P0);
  k_gemm<32,64,64,1><<<dim3(625,1,1), 256, 0, stream>>>(P0, 32, wp_e1, b_e1, X1, nullptr);
  // encoder2: x2 = relu(agg(x1) @ W2 + b2)
  k_gcn_agg<64,2><<<Nn/4, 256, 0, stream>>>(X1, dinv, row_start, erec, nullptr, nullptr, nullptr, (unsigned short*)S3);
  k_gemm<64,128,128,1><<<dim3(625,2,1), 256, 0, stream>>>((unsigned short*)S3, 64, wp_e2, b_e2, X2, nullptr);
  // encoder3 (GAT): x3 = relu(headmm(gat_agg(x2)) + b3)
  k_attn_in<128><<<Nn/4, 256, 0, stream>>>(X2, wsF_e3, wdF_e3, aSb, aDb);
  k_gat_prep<<<Nn/4, 256, 0, stream>>>(aSb, aDb, row_start, csr, alphaE, fS4, rin4);
  k_gat_agg2<128><<<Nn/4, 256, 0, stream>>>(X2, csr, alphaE, fS4, rin4, row_start, S1);
  k_gemm<128,512,128,2><<<dim3(625,2,4), 256, 0, stream>>>(S1, 512, wp_e3, b_e3, nullptr, S2);
  // decoder1: h4 = relu(agg(x3 @ Wd1) + bd1) + x2
  k_gemm<512,128,128,0><<<dim3(625,2,1), 256, 0, stream>>>(S2, 512, wp_d1, nullptr, (float*)S3, nullptr);
  k_gcn_agg<128,3><<<Nn/4, 256, 0, stream>>>((float*)S3, dinv, row_start, erec, b_d1, X2, nullptr, S1);
  // decoder2: h5 = relu(agg(h4 @ Wd2) + bd2) + x1
  k_gemm<128,64,64,0><<<dim3(625,1,1), 256, 0, stream>>>(S1, 128, wp_d2, nullptr, (float*)S2, nullptr);
  k_gcn_agg<64,1><<<Nn/4, 256, 0, stream>>>((float*)S2, dinv, row_start, erec, b_d2, X1, (float*)S3, nullptr);
  // decoder3 (GAT): h6 = relu(headmm(gat_agg(h5)) + bd3)
  k_attn_in<64><<<Nn/4, 256, 0, stream>>>((float*)S3, wsF_d3, wdF_d3, aSb, aDb);
  k_gat_prep<<<Nn/4, 256, 0, stream>>>(aSb, aDb, row_start, csr, alphaE, fS4, rin4);
  k_gat_agg2<64><<<Nn/4, 256, 0, stream>>>((float*)S3, csr, alphaE, fS4, rin4, row_start, S1);
  k_gemm<64,256,64,2><<<dim3(625,1,4), 256, 0, stream>>>(S1, 256, wp_d3, b_d3, nullptr, S2);
  // MLP head
  k_gemm<256,256,256,2><<<dim3(625,4,1), 256, 0, stream>>>(S2, 256, wp_fc1, b_fc1, nullptr, S1);
  k_gemm<256,128,128,1><<<dim3(625,2,1), 256, 0, stream>>>(S1, 256, wp_fc2, b_fc2, (float*)S2, nullptr);
  k_mm_fin<<<Nn/4, 256, 0, stream>>>((float*)S2, w_fin, b_fin, (float*)d_out);
}

// Round 9
// 349.271 us; speedup vs baseline: 1.2433x; 1.0028x over previous
//
#include <hip/hip_runtime.h>
#include <cstdint>
#include <cstddef>

static constexpr int Nn = 20000;
static constexpr int Ee = 320000;

typedef _Float16 half8 __attribute__((ext_vector_type(8)));
typedef float f32x4 __attribute__((ext_vector_type(4)));

__device__ __forceinline__ float lrelu02(float x){ return fmaxf(x, 0.2f*x); }
__device__ __forceinline__ float af(int x){ return __int_as_float(x); }

// split v = hi + lo/2048, hi/lo fp16 (lo pre-scaled to stay in normal range)
__device__ __forceinline__ void packhl(float v, unsigned short& h, unsigned short& l){
  _Float16 hh = (_Float16)v;
  _Float16 ll = (_Float16)((v - (float)hh) * 2048.0f);
  h = __builtin_bit_cast(unsigned short, hh);
  l = __builtin_bit_cast(unsigned short, ll);
}

// ---------------- CSR build ----------------
__global__ void k_scan(const int* __restrict__ cnt, int* __restrict__ row_start,
                       float* __restrict__ dinv){
  __shared__ int part[1024];
  int tid = threadIdx.x;
  const int PER = 20;
  int base = tid*PER;
  int s = 0;
  for (int i = 0; i < PER; ++i){ int idx = base+i; if (idx < Nn) s += cnt[idx]; }
  part[tid] = s; __syncthreads();
  for (int off = 1; off < 1024; off <<= 1){
    int v = (tid >= off) ? part[tid-off] : 0;
    __syncthreads();
    part[tid] += v;
    __syncthreads();
  }
  int run = (tid == 0) ? 0 : part[tid-1];
  for (int i = 0; i < PER; ++i){
    int idx = base+i;
    if (idx < Nn){
      row_start[idx] = run;
      int c = cnt[idx];
      run += c;
      dinv[idx] = rsqrtf((float)(c+1));
    }
  }
  if (tid == 1023) row_start[Nn] = run;
}

__global__ void k_scatter(const int* __restrict__ src, const int* __restrict__ dst,
                          const int* __restrict__ row_start, int* __restrict__ fill,
                          int* __restrict__ csr, const float* __restrict__ dinv,
                          int2* __restrict__ erec){
  int e = blockIdx.x*256 + threadIdx.x;
  if (e < Ee){
    int d = dst[e];
    int pos = row_start[d] + atomicAdd(&fill[d], 1);
    int u = src[e];
    csr[pos] = u;
    erec[pos] = make_int2(u, __float_as_int(dinv[u]));
  }
}

// ---------------- mega init: weight fragment packs + attention folds + edge count ----------------
// fragment pack layout: pos = ((col>>4)*(K/8) + (k>>3))*16 + (col&15))*8 + (k&7); lo at +K*J
struct PrepArgs {
  const float *w_e1,*w_e2,*w_e3,*w_d1,*w_d2,*w_d3,*w_fc1,*w_fc2;
  unsigned short *p_e1,*p_e2,*p_e3,*p_d1,*p_d2,*p_d3,*p_fc1,*p_fc2;
  const float *as_e3,*ad_e3,*as_d3,*ad_d3;
  float *wsF_e3,*wdF_e3,*wsF_d3,*wdF_d3;
  const int* dst;
  int* cnt;
};

__device__ __forceinline__ void packw_one(const float* __restrict__ W,
                                          unsigned short* __restrict__ out,
                                          int i, int jlog, int K){
  int k = i >> jlog, col = i - (k << jlog);
  unsigned short h, l; packhl(W[i], h, l);
  size_t pos = ((size_t)((col>>4)*(K>>3) + (k>>3))*16 + (col&15))*8 + (k&7);
  out[pos] = h;
  out[pos + ((size_t)K << jlog)] = l;
}

__global__ void k_init(PrepArgs a){
  int gi = blockIdx.x*256 + threadIdx.x;
  if (gi >= 264960){
    int e = gi - 264960;
    if (e < Ee) atomicAdd(&a.cnt[a.dst[e]], 1);
    return;
  }
  int i = gi;
  if      (i <   2048) packw_one(a.w_e1,  a.p_e1,  i,          6,  32);
  else if (i <  10240) packw_one(a.w_e2,  a.p_e2,  i-2048,     7,  64);
  else if (i <  75776) packw_one(a.w_e3,  a.p_e3,  i-10240,    9, 128);
  else if (i < 141312) packw_one(a.w_d1,  a.p_d1,  i-75776,    7, 512);
  else if (i < 149504) packw_one(a.w_d2,  a.p_d2,  i-141312,   6, 128);
  else if (i < 165888) packw_one(a.w_d3,  a.p_d3,  i-149504,   8,  64);
  else if (i < 231424) packw_one(a.w_fc1, a.p_fc1, i-165888,   8, 256);
  else if (i < 264192) packw_one(a.w_fc2, a.p_fc2, i-231424,   7, 256);
  else if (i < 264704){           // fold e3: INC=128, C=128
    int t = i - 264192;
    int h = t >> 7, k = t & 127;
    float s = 0.f, d = 0.f;
    #pragma unroll 4
    for (int c = 0; c < 128; ++c){
      float wv = a.w_e3[(size_t)k*512 + h*128 + c];
      s = fmaf(wv, a.as_e3[h*128 + c], s);
      d = fmaf(wv, a.ad_e3[h*128 + c], d);
    }
    a.wsF_e3[h*128 + k] = s;
    a.wdF_e3[h*128 + k] = d;
  } else {                        // fold d3: INC=64, C=64
    int t = i - 264704;
    int h = t >> 6, k = t & 63;
    float s = 0.f, d = 0.f;
    #pragma unroll 4
    for (int c = 0; c < 64; ++c){
      float wv = a.w_d3[(size_t)k*256 + h*64 + c];
      s = fmaf(wv, a.as_d3[h*64 + c], s);
      d = fmaf(wv, a.ad_d3[h*64 + c], d);
    }
    a.wsF_d3[h*64 + k] = s;
    a.wdF_d3[h*64 + k] = d;
  }
}

// ---------------- GCN aggregation (uniform record loads) ----------------
// POST: 0 = f32 raw; 1 = f32 relu(+bias)+skip; 2 = pack raw; 3 = relu+bias+skip then pack
template<int C, int POST>
__global__ __launch_bounds__(256) void k_gcn_agg(
    const float* __restrict__ h, const float* __restrict__ dinv,
    const int* __restrict__ row_start, const int2* __restrict__ erec,
    const float* __restrict__ bias, const float* __restrict__ skip,
    float* __restrict__ outf, unsigned short* __restrict__ outp){
  int v = blockIdx.x*4 + (threadIdx.x >> 6);
  int lane = threadIdx.x & 63;
  int s = __builtin_amdgcn_readfirstlane(row_start[v]);
  int e = __builtin_amdgcn_readfirstlane(row_start[v+1]);
  float dv = dinv[v];
  const int c = (C==32) ? (lane & 31) : ((C==128) ? lane*2 : lane);

  float a0 = 0.f, a1 = 0.f;
  if constexpr (C == 32){
    int half = lane >> 5;
    int j = s + half;
    for (; j + 2 < e; j += 4){
      int2 r0 = erec[j], r1 = erec[j+2];
      float t0 = h[(size_t)r0.x*32 + c];
      float t1 = h[(size_t)r1.x*32 + c];
      a0 = fmaf(af(r0.y), t0, a0);
      a0 = fmaf(af(r1.y), t1, a0);
    }
    if (j < e){
      int2 r0 = erec[j];
      a0 = fmaf(af(r0.y), h[(size_t)r0.x*32 + c], a0);
    }
    a0 += __shfl_xor(a0, 32);
  } else if constexpr (C == 128){
    int j = s;
    for (; j + 4 <= e; j += 4){
      int2 r0 = erec[j], r1 = erec[j+1], r2 = erec[j+2], r3 = erec[j+3];
      float2 t0 = *(const float2*)&h[(size_t)r0.x*128 + c];
      float2 t1 = *(const float2*)&h[(size_t)r1.x*128 + c];
      float2 t2 = *(const float2*)&h[(size_t)r2.x*128 + c];
      float2 t3 = *(const float2*)&h[(size_t)r3.x*128 + c];
      a0=fmaf(af(r0.y),t0.x,a0); a1=fmaf(af(r0.y),t0.y,a1);
      a0=fmaf(af(r1.y),t1.x,a0); a1=fmaf(af(r1.y),t1.y,a1);
      a0=fmaf(af(r2.y),t2.x,a0); a1=fmaf(af(r2.y),t2.y,a1);
      a0=fmaf(af(r3.y),t3.x,a0); a1=fmaf(af(r3.y),t3.y,a1);
    }
    for (; j < e; ++j){
      int2 r = erec[j];
      float2 t = *(const float2*)&h[(size_t)r.x*128 + c];
      a0 = fmaf(af(r.y), t.x, a0); a1 = fmaf(af(r.y), t.y, a1);
    }
  } else { // C == 64
    int j = s;
    for (; j + 4 <= e; j += 4){
      int2 r0 = erec[j], r1 = erec[j+1], r2 = erec[j+2], r3 = erec[j+3];
      float t0 = h[(size_t)r0.x*64 + c];
      float t1 = h[(size_t)r1.x*64 + c];
      float t2 = h[(size_t)r2.x*64 + c];
      float t3 = h[(size_t)r3.x*64 + c];
      a0=fmaf(af(r0.y),t0,a0); a0=fmaf(af(r1.y),t1,a0);
      a0=fmaf(af(r2.y),t2,a0); a0=fmaf(af(r3.y),t3,a0);
    }
    for (; j < e; ++j){
      int2 r = erec[j];
      a0 = fmaf(af(r.y), h[(size_t)r.x*64 + c], a0);
    }
  }

  if constexpr (C == 128){
    float2 hv = *(const float2*)&h[(size_t)v*128 + c];
    float vx = fmaf(a0, dv, hv.x*dv*dv);
    float vy = fmaf(a1, dv, hv.y*dv*dv);
    if constexpr (POST & 1){
      float2 bv = *(const float2*)&bias[c];
      float2 sk = *(const float2*)&skip[(size_t)v*128 + c];
      vx = fmaxf(vx + bv.x, 0.f) + sk.x;
      vy = fmaxf(vy + bv.y, 0.f) + sk.y;
    }
    if constexpr (POST & 2){
      unsigned short h0,l0,h1,l1; packhl(vx,h0,l0); packhl(vy,h1,l1);
      *(unsigned int*)&outp[(size_t)v*128 + c] = (unsigned)h0 | ((unsigned)h1<<16);
      *(unsigned int*)&outp[(size_t)v*128 + c + (size_t)Nn*128] = (unsigned)l0 | ((unsigned)l1<<16);
    } else {
      *(float2*)&outf[(size_t)v*128 + c] = make_float2(vx, vy);
    }
  } else if constexpr (C == 64){
    float val = fmaf(a0, dv, h[(size_t)v*64 + c]*dv*dv);
    if constexpr (POST & 1){
      val = fmaxf(val + bias[c], 0.f) + skip[(size_t)v*64 + c];
    }
    if constexpr (POST & 2){
      unsigned short hh,ll; packhl(val,hh,ll);
      outp[(size_t)v*64 + c] = hh;
      outp[(size_t)v*64 + c + (size_t)Nn*64] = ll;
    } else {
      outf[(size_t)v*64 + c] = val;
    }
  } else { // C == 32, pack only
    float val = fmaf(a0, dv, h[(size_t)v*32 + c]*dv*dv);
    if (lane < 32){
      unsigned short hh,ll; packhl(val,hh,ll);
      outp[(size_t)v*32 + c] = hh;
      outp[(size_t)v*32 + c + (size_t)Nn*32] = ll;
    }
  }
}

// ---------------- attention coefficients from the INPUT ----------------
template<int INC>
__global__ __launch_bounds__(256) void k_attn_in(
    const float* __restrict__ X, const float* __restrict__ wsF, const float* __restrict__ wdF,
    float* __restrict__ aS, float* __restrict__ aD){
  int v = blockIdx.x*4 + (threadIdx.x >> 6);
  int lane = threadIdx.x & 63;
  float x0 = X[(size_t)v*INC + lane];
  float x1 = (INC == 128) ? X[(size_t)v*INC + 64 + lane] : 0.f;
  float s[4], d[4];
  #pragma unroll
  for (int h = 0; h < 4; ++h){
    s[h] = x0*wsF[h*INC + lane];
    d[h] = x0*wdF[h*INC + lane];
    if constexpr (INC == 128){
      s[h] = fmaf(x1, wsF[h*INC + 64 + lane], s[h]);
      d[h] = fmaf(x1, wdF[h*INC + 64 + lane], d[h]);
    }
  }
  #pragma unroll
  for (int off = 32; off; off >>= 1){
    #pragma unroll
    for (int h = 0; h < 4; ++h){
      s[h] += __shfl_xor(s[h], off);
      d[h] += __shfl_xor(d[h], off);
    }
  }
  if (lane == 0){
    *(float4*)&aS[v*4] = make_float4(s[0], s[1], s[2], s[3]);
    *(float4*)&aD[v*4] = make_float4(d[0], d[1], d[2], d[3]);
  }
}

// ---------------- fused GAT: per-64-edge chunks {lane-parallel exp -> LDS} + record-load agg ----------------
// no max-shift (logits O(1), exp safe — verified round 8). Packs output hi/lo.
template<int INC>   // 128 (e3) or 64 (d3)
__global__ __launch_bounds__(256) void k_gat_fused(
    const float* __restrict__ X, const int* __restrict__ csr,
    const float* __restrict__ aS, const float* __restrict__ aD,
    const int* __restrict__ row_start, unsigned short* __restrict__ outp){
  __shared__ float4 sF[4][64];
  int wv = threadIdx.x >> 6;
  int v = blockIdx.x*4 + wv;
  int lane = threadIdx.x & 63;
  int s = __builtin_amdgcn_readfirstlane(row_start[v]);
  int e = __builtin_amdgcn_readfirstlane(row_start[v+1]);
  const int c2 = lane*2;

  float4 tD = *(const float4*)&aD[v*4];
  float ad0=tD.x, ad1=tD.y, ad2=tD.z, ad3=tD.w;
  float4 tS = *(const float4*)&aS[v*4];

  float sd0=0.f, sd1=0.f, sd2=0.f, sd3=0.f;
  float2 acc0={0,0}, acc1={0,0}, acc2={0,0}, acc3={0,0};
  float ac0=0.f, ac1=0.f, ac2=0.f, ac3=0.f;

  for (int base = s; base < e; base += 64){
    int i = base + lane;
    float4 f = {0.f, 0.f, 0.f, 0.f};
    if (i < e){
      int u = csr[i];
      float4 a4 = *(const float4*)&aS[u*4];
      f.x = __expf(lrelu02(a4.x+ad0));
      f.y = __expf(lrelu02(a4.y+ad1));
      f.z = __expf(lrelu02(a4.z+ad2));
      f.w = __expf(lrelu02(a4.w+ad3));
      sd0 += f.x; sd1 += f.y; sd2 += f.z; sd3 += f.w;
    }
    sF[wv][lane] = f;    // same-wave producer/consumer: no barrier needed
    int cnt = min(64, e - base);
    int j = 0;
    for (; j + 4 <= cnt; j += 4){
      int u0=csr[base+j], u1=csr[base+j+1], u2=csr[base+j+2], u3=csr[base+j+3];
      float4 f0=sF[wv][j], f1=sF[wv][j+1], f2=sF[wv][j+2], f3=sF[wv][j+3];
      if constexpr (INC == 128){
        float2 x0 = *(const float2*)&X[(size_t)u0*128 + c2];
        float2 x1 = *(const float2*)&X[(size_t)u1*128 + c2];
        float2 x2 = *(const float2*)&X[(size_t)u2*128 + c2];
        float2 x3 = *(const float2*)&X[(size_t)u3*128 + c2];
        acc0.x=fmaf(f0.x,x0.x,acc0.x); acc0.y=fmaf(f0.x,x0.y,acc0.y);
        acc1.x=fmaf(f0.y,x0.x,acc1.x); acc1.y=fmaf(f0.y,x0.y,acc1.y);
        acc2.x=fmaf(f0.z,x0.x,acc2.x); acc2.y=fmaf(f0.z,x0.y,acc2.y);
        acc3.x=fmaf(f0.w,x0.x,acc3.x); acc3.y=fmaf(f0.w,x0.y,acc3.y);
        acc0.x=fmaf(f1.x,x1.x,acc0.x); acc0.y=fmaf(f1.x,x1.y,acc0.y);
        acc1.x=fmaf(f1.y,x1.x,acc1.x); acc1.y=fmaf(f1.y,x1.y,acc1.y);
        acc2.x=fmaf(f1.z,x1.x,acc2.x); acc2.y=fmaf(f1.z,x1.y,acc2.y);
        acc3.x=fmaf(f1.w,x1.x,acc3.x); acc3.y=fmaf(f1.w,x1.y,acc3.y);
        acc0.x=fmaf(f2.x,x2.x,acc0.x); acc0.y=fmaf(f2.x,x2.y,acc0.y);
        acc1.x=fmaf(f2.y,x2.x,acc1.x); acc1.y=fmaf(f2.y,x2.y,acc1.y);
        acc2.x=fmaf(f2.z,x2.x,acc2.x); acc2.y=fmaf(f2.z,x2.y,acc2.y);
        acc3.x=fmaf(f2.w,x2.x,acc3.x); acc3.y=fmaf(f2.w,x2.y,acc3.y);
        acc0.x=fmaf(f3.x,x3.x,acc0.x); acc0.y=fmaf(f3.x,x3.y,acc0.y);
        acc1.x=fmaf(f3.y,x3.x,acc1.x); acc1.y=fmaf(f3.y,x3.y,acc1.y);
        acc2.x=fmaf(f3.z,x3.x,acc2.x); acc2.y=fmaf(f3.z,x3.y,acc2.y);
        acc3.x=fmaf(f3.w,x3.x,acc3.x); acc3.y=fmaf(f3.w,x3.y,acc3.y);
      } else {
        float x0 = X[(size_t)u0*64 + lane];
        float x1 = X[(size_t)u1*64 + lane];
        float x2 = X[(size_t)u2*64 + lane];
        float x3 = X[(size_t)u3*64 + lane];
        ac0=fmaf(f0.x,x0,ac0); ac1=fmaf(f0.y,x0,ac1); ac2=fmaf(f0.z,x0,ac2); ac3=fmaf(f0.w,x0,ac3);
        ac0=fmaf(f1.x,x1,ac0); ac1=fmaf(f1.y,x1,ac1); ac2=fmaf(f1.z,x1,ac2); ac3=fmaf(f1.w,x1,ac3);
        ac0=fmaf(f2.x,x2,ac0); ac1=fmaf(f2.y,x2,ac1); ac2=fmaf(f2.z,x2,ac2); ac3=fmaf(f2.w,x2,ac3);
        ac0=fmaf(f3.x,x3,ac0); ac1=fmaf(f3.y,x3,ac1); ac2=fmaf(f3.z,x3,ac2); ac3=fmaf(f3.w,x3,ac3);
      }
    }
    for (; j < cnt; ++j){
      int u = csr[base+j];
      float4 f4 = sF[wv][j];
      if constexpr (INC == 128){
        float2 xu = *(const float2*)&X[(size_t)u*128 + c2];
        acc0.x=fmaf(f4.x,xu.x,acc0.x); acc0.y=fmaf(f4.x,xu.y,acc0.y);
        acc1.x=fmaf(f4.y,xu.x,acc1.x); acc1.y=fmaf(f4.y,xu.y,acc1.y);
        acc2.x=fmaf(f4.z,xu.x,acc2.x); acc2.y=fmaf(f4.z,xu.y,acc2.y);
        acc3.x=fmaf(f4.w,xu.x,acc3.x); acc3.y=fmaf(f4.w,xu.y,acc3.y);
      } else {
        float xu = X[(size_t)u*64 + lane];
        ac0=fmaf(f4.x,xu,ac0); ac1=fmaf(f4.y,xu,ac1); ac2=fmaf(f4.z,xu,ac2); ac3=fmaf(f4.w,xu,ac3);
      }
    }
  }

  #pragma unroll
  for (int off = 32; off; off >>= 1){
    sd0 += __shfl_xor(sd0, off);
    sd1 += __shfl_xor(sd1, off);
    sd2 += __shfl_xor(sd2, off);
    sd3 += __shfl_xor(sd3, off);
  }
  float es0=__expf(lrelu02(tS.x+ad0)), es1=__expf(lrelu02(tS.y+ad1));
  float es2=__expf(lrelu02(tS.z+ad2)), es3=__expf(lrelu02(tS.w+ad3));
  float r0=1.f/(sd0+es0), r1=1.f/(sd1+es1), r2=1.f/(sd2+es2), r3=1.f/(sd3+es3);

  if constexpr (INC == 128){
    float2 xv = *(const float2*)&X[(size_t)v*128 + c2];
    const size_t loOff = (size_t)Nn*512;
    float ox, oy; unsigned short h0,l0,h1,l1;
    ox=(acc0.x+es0*xv.x)*r0; oy=(acc0.y+es0*xv.y)*r0;
    packhl(ox,h0,l0); packhl(oy,h1,l1);
    *(unsigned int*)&outp[(size_t)v*512 +   0 + c2] = (unsigned)h0|((unsigned)h1<<16);
    *(unsigned int*)&outp[(size_t)v*512 +   0 + c2 + loOff] = (unsigned)l0|((unsigned)l1<<16);
    ox=(acc1.x+es1*xv.x)*r1; oy=(acc1.y+es1*xv.y)*r1;
    packhl(ox,h0,l0); packhl(oy,h1,l1);
    *(unsigned int*)&outp[(size_t)v*512 + 128 + c2] = (unsigned)h0|((unsigned)h1<<16);
    *(unsigned int*)&outp[(size_t)v*512 + 128 + c2 + loOff] = (unsigned)l0|((unsigned)l1<<16);
    ox=(acc2.x+es2*xv.x)*r2; oy=(acc2.y+es2*xv.y)*r2;
    packhl(ox,h0,l0); packhl(oy,h1,l1);
    *(unsigned int*)&outp[(size_t)v*512 + 256 + c2] = (unsigned)h0|((unsigned)h1<<16);
    *(unsigned int*)&outp[(size_t)v*512 + 256 + c2 + loOff] = (unsigned)l0|((unsigned)l1<<16);
    ox=(acc3.x+es3*xv.x)*r3; oy=(acc3.y+es3*xv.y)*r3;
    packhl(ox,h0,l0); packhl(oy,h1,l1);
    *(unsigned int*)&outp[(size_t)v*512 + 384 + c2] = (unsigned)h0|((unsigned)h1<<16);
    *(unsigned int*)&outp[(size_t)v*512 + 384 + c2 + loOff] = (unsigned)l0|((unsigned)l1<<16);
  } else {
    float xv = X[(size_t)v*64 + lane];
    const size_t loOff = (size_t)Nn*256;
    unsigned short hh,ll;
    float o;
    o = (ac0+es0*xv)*r0; packhl(o,hh,ll);
    outp[(size_t)v*256 +   0 + lane] = hh; outp[(size_t)v*256 +   0 + lane + loOff] = ll;
    o = (ac1+es1*xv)*r1; packhl(o,hh,ll);
    outp[(size_t)v*256 +  64 + lane] = hh; outp[(size_t)v*256 +  64 + lane + loOff] = ll;
    o = (ac2+es2*xv)*r2; packhl(o,hh,ll);
    outp[(size_t)v*256 + 128 + lane] = hh; outp[(size_t)v*256 + 128 + lane + loOff] = ll;
    o = (ac3+es3*xv)*r3; packhl(o,hh,ll);
    outp[(size_t)v*256 + 192 + lane] = hh; outp[(size_t)v*256 + 192 + lane + loOff] = ll;
  }
}

// ---------------- MFMA GEMM: BM=64, BN=64, BK=32; 4 waves, wave = 16 rows x 64 cols ----------------
// out[n, z*Jh + j] = sum_k A[n, z*K + k] * W[k, z*Jh + j]
// A packed: hi u16 [Nn][lda], lo at +Nn*lda.  W fragment-packed (k_init), lo at +K*J.
// EPI: 0 = f32 raw; 1 = f32 relu(acc+bias); 2 = relu(acc+bias) then pack (lo at +Nn*J)
template<int K, int J, int Jh, int EPI>
__global__ __launch_bounds__(256) void k_gemm(
    const unsigned short* __restrict__ Ahi, int lda,
    const unsigned short* __restrict__ Wp,
    const float* __restrict__ bias,
    float* __restrict__ outf, unsigned short* __restrict__ outp){
  __shared__ unsigned short sAhi[4*64*8], sAlo[4*64*8];   // 64 rows x 32 k, frag-ordered
  __shared__ unsigned short sBhi[4*64*8], sBlo[4*64*8];   // 32 k x 64 cols, frag-ordered

  const int tid  = threadIdx.x;
  const int lane = tid & 63, w = tid >> 6;
  const int rb = blockIdx.x;
  const int colbase = blockIdx.z*Jh + blockIdx.y*64;
  const int akoff   = blockIdx.z*K;
  const size_t AloOff = (size_t)Nn*lda;
  const size_t WloOff = (size_t)K*J;

  f32x4 accH[4] = {{0,0,0,0},{0,0,0,0},{0,0,0,0},{0,0,0,0}};
  f32x4 accM[4] = {{0,0,0,0},{0,0,0,0},{0,0,0,0},{0,0,0,0}};

  // A staging: thread -> row tid>>2 (0..63), k-offset (tid&3)*8: one uint4 hi + one lo
  const int arow = tid >> 2;
  const int akq  = (tid & 3) * 8;
  int agrow = rb*64 + arow; if (agrow >= Nn) agrow = Nn - 1;
  const unsigned short* Ag = Ahi + (size_t)agrow*lda + akoff + akq;
  const int aw_idx = (((arow>>4)*4 + (akq>>3))*16 + (arow&15))*8;
  // B staging: thread -> col tid&63, k-group tid>>6: one uint4 hi + one lo (coalesced frag-packed)
  const int bcol = tid & 63;
  const int bkg  = tid >> 6;
  const int bw_idx = (((bcol>>4)*4 + bkg)*16 + (bcol&15))*8;
  const int cf_g  = (colbase>>4) + (bcol>>4);
  const size_t wbase = ((size_t)cf_g*(K/8)*16 + (size_t)(bcol&15))*8;

  #pragma unroll 1
  for (int ks = 0; ks < K/32; ++ks){
    if (ks) __syncthreads();
    {
      const unsigned short* p = Ag + ks*32;
      uint4 hv = *(const uint4*)p;
      uint4 lv = *(const uint4*)(p + AloOff);
      *(uint4*)&sAhi[aw_idx] = hv;
      *(uint4*)&sAlo[aw_idx] = lv;
    }
    {
      size_t goff = wbase + (size_t)(ks*4 + bkg)*128;
      uint4 hv = *(const uint4*)&Wp[goff];
      uint4 lv = *(const uint4*)&Wp[goff + WloOff];
      *(uint4*)&sBhi[bw_idx] = hv;
      *(uint4*)&sBlo[bw_idx] = lv;
    }
    __syncthreads();

    half8 aH = *(const half8*)&sAhi[(w*64 + lane)*8];
    half8 aL = *(const half8*)&sAlo[(w*64 + lane)*8];
    #pragma unroll
    for (int cf = 0; cf < 4; ++cf){
      half8 bH = *(const half8*)&sBhi[(cf*64 + lane)*8];
      half8 bL = *(const half8*)&sBlo[(cf*64 + lane)*8];
      accH[cf] = __builtin_amdgcn_mfma_f32_16x16x32_f16(aH, bH, accH[cf], 0, 0, 0);
      accM[cf] = __builtin_amdgcn_mfma_f32_16x16x32_f16(aH, bL, accM[cf], 0, 0, 0);
      accM[cf] = __builtin_amdgcn_mfma_f32_16x16x32_f16(aL, bH, accM[cf], 0, 0, 0);
    }
  }

  // epilogue: C/D layout col = lane&15, row = (lane>>4)*4 + r
  #pragma unroll
  for (int cf = 0; cf < 4; ++cf){
    int col = colbase + cf*16 + (lane & 15);
    float bv = (EPI >= 1) ? bias[col] : 0.f;
    #pragma unroll
    for (int r = 0; r < 4; ++r){
      int row = rb*64 + w*16 + ((lane>>4)*4 + r);
      if (row < Nn){
        float v = accH[cf][r] + accM[cf][r]*(1.0f/2048.0f);
        if constexpr (EPI >= 1) v = fmaxf(v + bv, 0.f);
        if constexpr (EPI == 2){
          unsigned short hh, ll; packhl(v, hh, ll);
          outp[(size_t)row*J + col] = hh;
          outp[(size_t)row*J + col + (size_t)Nn*J] = ll;
        } else {
          outf[(size_t)row*J + col] = v;
        }
      }
    }
  }
}

// ---------------- final 128 -> 4 matmul (+bias), one wave per row ----------------
__global__ __launch_bounds__(256) void k_mm_fin(
    const float* __restrict__ A, const float* __restrict__ W,
    const float* __restrict__ bias, float* __restrict__ out){
  int row = blockIdx.x*4 + (threadIdx.x >> 6);
  int lane = threadIdx.x & 63;
  float a0 = A[(size_t)row*128 + lane];
  float a1 = A[(size_t)row*128 + 64 + lane];
  float4 w0 = ((const float4*)W)[lane];
  float4 w1 = ((const float4*)W)[64 + lane];
  float p0 = fmaf(a1, w1.x, a0*w0.x);
  float p1 = fmaf(a1, w1.y, a0*w0.y);
  float p2 = fmaf(a1, w1.z, a0*w0.z);
  float p3 = fmaf(a1, w1.w, a0*w0.w);
  #pragma unroll
  for (int off = 32; off; off >>= 1){
    p0 += __shfl_xor(p0, off);
    p1 += __shfl_xor(p1, off);
    p2 += __shfl_xor(p2, off);
    p3 += __shfl_xor(p3, off);
  }
  if (lane == 0){
    float4 bv = *(const float4*)bias;
    *(float4*)&out[(size_t)row*4] = make_float4(p0+bv.x, p1+bv.y, p2+bv.z, p3+bv.w);
  }
}

// ---------------- launch ----------------
extern "C" void kernel_launch(void* const* d_in, const int* in_sizes, int n_in,
                              void* d_out, int out_size, void* d_ws, size_t ws_size,
                              hipStream_t stream){
  const float* x     = (const float*)d_in[0];
  const int*   ei    = (const int*)  d_in[1];
  const float* w_e1  = (const float*)d_in[2];
  const float* b_e1  = (const float*)d_in[3];
  const float* w_e2  = (const float*)d_in[4];
  const float* b_e2  = (const float*)d_in[5];
  const float* w_e3  = (const float*)d_in[6];
  const float* as_e3 = (const float*)d_in[7];
  const float* ad_e3 = (const float*)d_in[8];
  const float* b_e3  = (const float*)d_in[9];
  const float* w_d1  = (const float*)d_in[10];
  const float* b_d1  = (const float*)d_in[11];
  const float* w_d2  = (const float*)d_in[12];
  const float* b_d2  = (const float*)d_in[13];
  const float* w_d3  = (const float*)d_in[14];
  const float* as_d3 = (const float*)d_in[15];
  const float* ad_d3 = (const float*)d_in[16];
  const float* b_d3  = (const float*)d_in[17];
  const float* w_fc1 = (const float*)d_in[18];
  const float* b_fc1 = (const float*)d_in[19];
  const float* w_fc2 = (const float*)d_in[20];
  const float* b_fc2 = (const float*)d_in[21];
  const float* w_fin = (const float*)d_in[22];
  const float* b_fin = (const float*)d_in[23];

  char* ws = (char*)d_ws;
  size_t off = 0;
  auto alloc = [&](size_t bytes)->char*{
    char* p = ws + off;
    off += (bytes + 255) & ~size_t(255);
    return p;
  };
  int*   cnt       = (int*)  alloc((size_t)Nn*4);      // cnt+fill contiguous: one memset
  int*   fill      = (int*)  alloc((size_t)Nn*4);
  int*   row_start = (int*)  alloc((size_t)(Nn+1)*4);
  int*   csr       = (int*)  alloc((size_t)Ee*4);
  float* dinv      = (float*)alloc((size_t)Nn*4);
  int2*  erec      = (int2*) alloc((size_t)Ee*8);
  float* aSb       = (float*)alloc((size_t)Nn*16);
  float* aDb       = (float*)alloc((size_t)Nn*16);
  float* wsF_e3    = (float*)alloc(4*128*4);
  float* wdF_e3    = (float*)alloc(4*128*4);
  float* wsF_d3    = (float*)alloc(4*64*4);
  float* wdF_d3    = (float*)alloc(4*64*4);
  // fragment-packed weights (hi then lo)
  unsigned short* wp_e1  = (unsigned short*)alloc((size_t)32*64*4);
  unsigned short* wp_e2  = (unsigned short*)alloc((size_t)64*128*4);
  unsigned short* wp_e3  = (unsigned short*)alloc((size_t)128*512*4);
  unsigned short* wp_d1  = (unsigned short*)alloc((size_t)512*128*4);
  unsigned short* wp_d2  = (unsigned short*)alloc((size_t)128*64*4);
  unsigned short* wp_d3  = (unsigned short*)alloc((size_t)64*256*4);
  unsigned short* wp_fc1 = (unsigned short*)alloc((size_t)256*256*4);
  unsigned short* wp_fc2 = (unsigned short*)alloc((size_t)256*128*4);
  // activations
  unsigned short* P0 = (unsigned short*)alloc((size_t)Nn*32*4);
  float* X1 = (float*)alloc((size_t)Nn*64*4);
  float* X2 = (float*)alloc((size_t)Nn*128*4);
  unsigned short* S1 = (unsigned short*)alloc((size_t)Nn*512*4);
  unsigned short* S2 = (unsigned short*)alloc((size_t)Nn*512*4);
  char*  S3 = alloc((size_t)Nn*128*4);

  const int* srcp = ei;
  const int* dstp = ei + Ee;

  hipMemsetAsync(cnt, 0, (size_t)(((size_t)Nn*4 + 255) & ~size_t(255)) + (size_t)Nn*4, stream);

  PrepArgs pa;
  pa.w_e1=w_e1; pa.w_e2=w_e2; pa.w_e3=w_e3; pa.w_d1=w_d1;
  pa.w_d2=w_d2; pa.w_d3=w_d3; pa.w_fc1=w_fc1; pa.w_fc2=w_fc2;
  pa.p_e1=wp_e1; pa.p_e2=wp_e2; pa.p_e3=wp_e3; pa.p_d1=wp_d1;
  pa.p_d2=wp_d2; pa.p_d3=wp_d3; pa.p_fc1=wp_fc1; pa.p_fc2=wp_fc2;
  pa.as_e3=as_e3; pa.ad_e3=ad_e3; pa.as_d3=as_d3; pa.ad_d3=ad_d3;
  pa.wsF_e3=wsF_e3; pa.wdF_e3=wdF_e3; pa.wsF_d3=wsF_d3; pa.wdF_d3=wdF_d3;
  pa.dst=dstp; pa.cnt=cnt;
  k_init<<<2285, 256, 0, stream>>>(pa);   // 1035 blocks prep + 1250 blocks edge-count

  k_scan<<<1, 1024, 0, stream>>>(cnt, row_start, dinv);
  k_scatter<<<(Ee+255)/256, 256, 0, stream>>>(srcp, dstp, row_start, fill, csr, dinv, erec);

  // encoder1: x1 = relu(agg(x) @ W1 + b1)
  k_gcn_agg<32,2><<<Nn/4, 256, 0, stream>>>(x, dinv, row_start, erec, nullptr, nullptr, nullptr, P0);
  k_gemm<32,64,64,1><<<dim3(313,1,1), 256, 0, stream>>>(P0, 32, wp_e1, b_e1, X1, nullptr);
  // encoder2: x2 = relu(agg(x1) @ W2 + b2)
  k_gcn_agg<64,2><<<Nn/4, 256, 0, stream>>>(X1, dinv, row_start, erec, nullptr, nullptr, nullptr, (unsigned short*)S3);
  k_gemm<64,128,128,1><<<dim3(313,2,1), 256, 0, stream>>>((unsigned short*)S3, 64, wp_e2, b_e2, X2, nullptr);
  // encoder3 (GAT): x3 = relu(headmm(gat_agg(x2)) + b3)
  k_attn_in<128><<<Nn/4, 256, 0, stream>>>(X2, wsF_e3, wdF_e3, aSb, aDb);
  k_gat_fused<128><<<Nn/4, 256, 0, stream>>>(X2, csr, aSb, aDb, row_start, S1);
  k_gemm<128,512,128,2><<<dim3(313,2,4), 256, 0, stream>>>(S1, 512, wp_e3, b_e3, nullptr, S2);
  // decoder1: h4 = relu(agg(x3 @ Wd1) + bd1) + x2
  k_gemm<512,128,128,0><<<dim3(313,2,1), 256, 0, stream>>>(S2, 512, wp_d1, nullptr, (float*)S3, nullptr);
  k_gcn_agg<128,3><<<Nn/4, 256, 0, stream>>>((float*)S3, dinv, row_start, erec, b_d1, X2, nullptr, S1);
  // decoder2: h5 = relu(agg(h4 @ Wd2) + bd2) + x1
  k_gemm<128,64,64,0><<<dim3(313,1,1), 256, 0, stream>>>(S1, 128, wp_d2, nullptr, (float*)S2, nullptr);
  k_gcn_agg<64,1><<<Nn/4, 256, 0, stream>>>((float*)S2, dinv, row_start, erec, b_d2, X1, (float*)S3, nullptr);
  // decoder3 (GAT): h6 = relu(headmm(gat_agg(h5)) + bd3)
  k_attn_in<64><<<Nn/4, 256, 0, stream>>>((float*)S3, wsF_d3, wdF_d3, aSb, aDb);
  k_gat_fused<64><<<Nn/4, 256, 0, stream>>>((float*)S3, csr, aSb, aDb, row_start, S1);
  k_gemm<64,256,64,2><<<dim3(313,1,4), 256, 0, stream>>>(S1, 256, wp_d3, b_d3, nullptr, S2);
  // MLP head
  k_gemm<256,256,256,2><<<dim3(313,4,1), 256, 0, stream>>>(S2, 256, wp_fc1, b_fc1, nullptr, S1);
  k_gemm<256,128,128,1><<<dim3(313,2,1), 256, 0, stream>>>(S1, 256, wp_fc2, b_fc2, (float*)S2, nullptr);
  k_mm_fin<<<Nn/4, 256, 0, stream>>>((float*)S2, w_fin, b_fin, (float*)d_out);
}

// Round 10
// 348.344 us; speedup vs baseline: 1.2466x; 1.0027x over previous
//
#include <hip/hip_runtime.h>
#include <cstdint>
#include <cstddef>

static constexpr int Nn = 20000;
static constexpr int Ee = 320000;

typedef _Float16 half8 __attribute__((ext_vector_type(8)));
typedef float f32x4 __attribute__((ext_vector_type(4)));

__device__ __forceinline__ float lrelu02(float x){ return fmaxf(x, 0.2f*x); }
__device__ __forceinline__ float af(int x){ return __int_as_float(x); }

// split v = hi + lo/2048, hi/lo fp16 (lo pre-scaled to stay in normal range)
__device__ __forceinline__ void packhl(float v, unsigned short& h, unsigned short& l){
  _Float16 hh = (_Float16)v;
  _Float16 ll = (_Float16)((v - (float)hh) * 2048.0f);
  h = __builtin_bit_cast(unsigned short, hh);
  l = __builtin_bit_cast(unsigned short, ll);
}

// ---------------- CSR build ----------------
__global__ void k_scan(const int* __restrict__ cnt, int* __restrict__ row_start,
                       float* __restrict__ dinv){
  __shared__ int part[1024];
  int tid = threadIdx.x;
  const int PER = 20;
  int base = tid*PER;
  int s = 0;
  for (int i = 0; i < PER; ++i){ int idx = base+i; if (idx < Nn) s += cnt[idx]; }
  part[tid] = s; __syncthreads();
  for (int off = 1; off < 1024; off <<= 1){
    int v = (tid >= off) ? part[tid-off] : 0;
    __syncthreads();
    part[tid] += v;
    __syncthreads();
  }
  int run = (tid == 0) ? 0 : part[tid-1];
  for (int i = 0; i < PER; ++i){
    int idx = base+i;
    if (idx < Nn){
      row_start[idx] = run;
      int c = cnt[idx];
      run += c;
      dinv[idx] = rsqrtf((float)(c+1));
    }
  }
  if (tid == 1023) row_start[Nn] = run;
}

__global__ void k_scatter(const int* __restrict__ src, const int* __restrict__ dst,
                          const int* __restrict__ row_start, int* __restrict__ fill,
                          int* __restrict__ csr, const float* __restrict__ dinv,
                          int2* __restrict__ erec){
  int e = blockIdx.x*256 + threadIdx.x;
  if (e < Ee){
    int d = dst[e];
    int pos = row_start[d] + atomicAdd(&fill[d], 1);
    int u = src[e];
    csr[pos] = u;
    erec[pos] = make_int2(u, __float_as_int(dinv[u]));
  }
}

// ---------------- mega init: weight fragment packs + attention folds + edge count ----------------
struct PrepArgs {
  const float *w_e1,*w_e2,*w_e3,*w_d1,*w_d2,*w_d3,*w_fc1,*w_fc2;
  unsigned short *p_e1,*p_e2,*p_e3,*p_d1,*p_d2,*p_d3,*p_fc1,*p_fc2;
  const float *as_e3,*ad_e3,*as_d3,*ad_d3;
  float *wsF_e3,*wdF_e3,*wsF_d3,*wdF_d3;
  const int* dst;
  int* cnt;
};

__device__ __forceinline__ void packw_one(const float* __restrict__ W,
                                          unsigned short* __restrict__ out,
                                          int i, int jlog, int K){
  int k = i >> jlog, col = i - (k << jlog);
  unsigned short h, l; packhl(W[i], h, l);
  size_t pos = ((size_t)((col>>4)*(K>>3) + (k>>3))*16 + (col&15))*8 + (k&7);
  out[pos] = h;
  out[pos + ((size_t)K << jlog)] = l;
}

__global__ void k_init(PrepArgs a){
  int gi = blockIdx.x*256 + threadIdx.x;
  if (gi >= 264960){
    int e = gi - 264960;
    if (e < Ee) atomicAdd(&a.cnt[a.dst[e]], 1);
    return;
  }
  int i = gi;
  if      (i <   2048) packw_one(a.w_e1,  a.p_e1,  i,          6,  32);
  else if (i <  10240) packw_one(a.w_e2,  a.p_e2,  i-2048,     7,  64);
  else if (i <  75776) packw_one(a.w_e3,  a.p_e3,  i-10240,    9, 128);
  else if (i < 141312) packw_one(a.w_d1,  a.p_d1,  i-75776,    7, 512);
  else if (i < 149504) packw_one(a.w_d2,  a.p_d2,  i-141312,   6, 128);
  else if (i < 165888) packw_one(a.w_d3,  a.p_d3,  i-149504,   8,  64);
  else if (i < 231424) packw_one(a.w_fc1, a.p_fc1, i-165888,   8, 256);
  else if (i < 264192) packw_one(a.w_fc2, a.p_fc2, i-231424,   7, 256);
  else if (i < 264704){           // fold e3: INC=128, C=128
    int t = i - 264192;
    int h = t >> 7, k = t & 127;
    float s = 0.f, d = 0.f;
    #pragma unroll 4
    for (int c = 0; c < 128; ++c){
      float wv = a.w_e3[(size_t)k*512 + h*128 + c];
      s = fmaf(wv, a.as_e3[h*128 + c], s);
      d = fmaf(wv, a.ad_e3[h*128 + c], d);
    }
    a.wsF_e3[h*128 + k] = s;
    a.wdF_e3[h*128 + k] = d;
  } else {                        // fold d3: INC=64, C=64
    int t = i - 264704;
    int h = t >> 6, k = t & 63;
    float s = 0.f, d = 0.f;
    #pragma unroll 4
    for (int c = 0; c < 64; ++c){
      float wv = a.w_d3[(size_t)k*256 + h*64 + c];
      s = fmaf(wv, a.as_d3[h*64 + c], s);
      d = fmaf(wv, a.ad_d3[h*64 + c], d);
    }
    a.wsF_d3[h*64 + k] = s;
    a.wdF_d3[h*64 + k] = d;
  }
}

// ---------------- GCN aggregation (uniform record loads, 8-deep gather ILP) ----------------
// POST: 0 = f32 raw; 1 = f32 relu(+bias)+skip; 2 = pack raw; 3 = relu+bias+skip then pack
template<int C, int POST>
__global__ __launch_bounds__(256) void k_gcn_agg(
    const float* __restrict__ h, const float* __restrict__ dinv,
    const int* __restrict__ row_start, const int2* __restrict__ erec,
    const float* __restrict__ bias, const float* __restrict__ skip,
    float* __restrict__ outf, unsigned short* __restrict__ outp){
  int v = blockIdx.x*4 + (threadIdx.x >> 6);
  int lane = threadIdx.x & 63;
  int s = __builtin_amdgcn_readfirstlane(row_start[v]);
  int e = __builtin_amdgcn_readfirstlane(row_start[v+1]);
  float dv = dinv[v];
  const int c = (C==32) ? (lane & 31) : ((C==128) ? lane*2 : lane);

  float a0 = 0.f, a1 = 0.f;
  if constexpr (C == 32){
    int half = lane >> 5;
    int j = s + half;
    for (; j + 2 < e; j += 4){
      int2 r0 = erec[j], r1 = erec[j+2];
      float t0 = h[(size_t)r0.x*32 + c];
      float t1 = h[(size_t)r1.x*32 + c];
      a0 = fmaf(af(r0.y), t0, a0);
      a0 = fmaf(af(r1.y), t1, a0);
    }
    if (j < e){
      int2 r0 = erec[j];
      a0 = fmaf(af(r0.y), h[(size_t)r0.x*32 + c], a0);
    }
    a0 += __shfl_xor(a0, 32);
  } else if constexpr (C == 128){
    int j = s;
    for (; j + 8 <= e; j += 8){
      int2 r0=erec[j],   r1=erec[j+1], r2=erec[j+2], r3=erec[j+3];
      int2 r4=erec[j+4], r5=erec[j+5], r6=erec[j+6], r7=erec[j+7];
      float2 t0 = *(const float2*)&h[(size_t)r0.x*128 + c];
      float2 t1 = *(const float2*)&h[(size_t)r1.x*128 + c];
      float2 t2 = *(const float2*)&h[(size_t)r2.x*128 + c];
      float2 t3 = *(const float2*)&h[(size_t)r3.x*128 + c];
      float2 t4 = *(const float2*)&h[(size_t)r4.x*128 + c];
      float2 t5 = *(const float2*)&h[(size_t)r5.x*128 + c];
      float2 t6 = *(const float2*)&h[(size_t)r6.x*128 + c];
      float2 t7 = *(const float2*)&h[(size_t)r7.x*128 + c];
      a0=fmaf(af(r0.y),t0.x,a0); a1=fmaf(af(r0.y),t0.y,a1);
      a0=fmaf(af(r1.y),t1.x,a0); a1=fmaf(af(r1.y),t1.y,a1);
      a0=fmaf(af(r2.y),t2.x,a0); a1=fmaf(af(r2.y),t2.y,a1);
      a0=fmaf(af(r3.y),t3.x,a0); a1=fmaf(af(r3.y),t3.y,a1);
      a0=fmaf(af(r4.y),t4.x,a0); a1=fmaf(af(r4.y),t4.y,a1);
      a0=fmaf(af(r5.y),t5.x,a0); a1=fmaf(af(r5.y),t5.y,a1);
      a0=fmaf(af(r6.y),t6.x,a0); a1=fmaf(af(r6.y),t6.y,a1);
      a0=fmaf(af(r7.y),t7.x,a0); a1=fmaf(af(r7.y),t7.y,a1);
    }
    for (; j + 4 <= e; j += 4){
      int2 r0 = erec[j], r1 = erec[j+1], r2 = erec[j+2], r3 = erec[j+3];
      float2 t0 = *(const float2*)&h[(size_t)r0.x*128 + c];
      float2 t1 = *(const float2*)&h[(size_t)r1.x*128 + c];
      float2 t2 = *(const float2*)&h[(size_t)r2.x*128 + c];
      float2 t3 = *(const float2*)&h[(size_t)r3.x*128 + c];
      a0=fmaf(af(r0.y),t0.x,a0); a1=fmaf(af(r0.y),t0.y,a1);
      a0=fmaf(af(r1.y),t1.x,a0); a1=fmaf(af(r1.y),t1.y,a1);
      a0=fmaf(af(r2.y),t2.x,a0); a1=fmaf(af(r2.y),t2.y,a1);
      a0=fmaf(af(r3.y),t3.x,a0); a1=fmaf(af(r3.y),t3.y,a1);
    }
    for (; j < e; ++j){
      int2 r = erec[j];
      float2 t = *(const float2*)&h[(size_t)r.x*128 + c];
      a0 = fmaf(af(r.y), t.x, a0); a1 = fmaf(af(r.y), t.y, a1);
    }
  } else { // C == 64
    int j = s;
    for (; j + 8 <= e; j += 8){
      int2 r0=erec[j],   r1=erec[j+1], r2=erec[j+2], r3=erec[j+3];
      int2 r4=erec[j+4], r5=erec[j+5], r6=erec[j+6], r7=erec[j+7];
      float t0 = h[(size_t)r0.x*64 + c];
      float t1 = h[(size_t)r1.x*64 + c];
      float t2 = h[(size_t)r2.x*64 + c];
      float t3 = h[(size_t)r3.x*64 + c];
      float t4 = h[(size_t)r4.x*64 + c];
      float t5 = h[(size_t)r5.x*64 + c];
      float t6 = h[(size_t)r6.x*64 + c];
      float t7 = h[(size_t)r7.x*64 + c];
      a0=fmaf(af(r0.y),t0,a0); a0=fmaf(af(r1.y),t1,a0);
      a0=fmaf(af(r2.y),t2,a0); a0=fmaf(af(r3.y),t3,a0);
      a0=fmaf(af(r4.y),t4,a0); a0=fmaf(af(r5.y),t5,a0);
      a0=fmaf(af(r6.y),t6,a0); a0=fmaf(af(r7.y),t7,a0);
    }
    for (; j + 4 <= e; j += 4){
      int2 r0 = erec[j], r1 = erec[j+1], r2 = erec[j+2], r3 = erec[j+3];
      float t0 = h[(size_t)r0.x*64 + c];
      float t1 = h[(size_t)r1.x*64 + c];
      float t2 = h[(size_t)r2.x*64 + c];
      float t3 = h[(size_t)r3.x*64 + c];
      a0=fmaf(af(r0.y),t0,a0); a0=fmaf(af(r1.y),t1,a0);
      a0=fmaf(af(r2.y),t2,a0); a0=fmaf(af(r3.y),t3,a0);
    }
    for (; j < e; ++j){
      int2 r = erec[j];
      a0 = fmaf(af(r.y), h[(size_t)r.x*64 + c], a0);
    }
  }

  if constexpr (C == 128){
    float2 hv = *(const float2*)&h[(size_t)v*128 + c];
    float vx = fmaf(a0, dv, hv.x*dv*dv);
    float vy = fmaf(a1, dv, hv.y*dv*dv);
    if constexpr (POST & 1){
      float2 bv = *(const float2*)&bias[c];
      float2 sk = *(const float2*)&skip[(size_t)v*128 + c];
      vx = fmaxf(vx + bv.x, 0.f) + sk.x;
      vy = fmaxf(vy + bv.y, 0.f) + sk.y;
    }
    if constexpr (POST & 2){
      unsigned short h0,l0,h1,l1; packhl(vx,h0,l0); packhl(vy,h1,l1);
      *(unsigned int*)&outp[(size_t)v*128 + c] = (unsigned)h0 | ((unsigned)h1<<16);
      *(unsigned int*)&outp[(size_t)v*128 + c + (size_t)Nn*128] = (unsigned)l0 | ((unsigned)l1<<16);
    } else {
      *(float2*)&outf[(size_t)v*128 + c] = make_float2(vx, vy);
    }
  } else if constexpr (C == 64){
    float val = fmaf(a0, dv, h[(size_t)v*64 + c]*dv*dv);
    if constexpr (POST & 1){
      val = fmaxf(val + bias[c], 0.f) + skip[(size_t)v*64 + c];
    }
    if constexpr (POST & 2){
      unsigned short hh,ll; packhl(val,hh,ll);
      outp[(size_t)v*64 + c] = hh;
      outp[(size_t)v*64 + c + (size_t)Nn*64] = ll;
    } else {
      outf[(size_t)v*64 + c] = val;
    }
  } else { // C == 32, pack only
    float val = fmaf(a0, dv, h[(size_t)v*32 + c]*dv*dv);
    if (lane < 32){
      unsigned short hh,ll; packhl(val,hh,ll);
      outp[(size_t)v*32 + c] = hh;
      outp[(size_t)v*32 + c + (size_t)Nn*32] = ll;
    }
  }
}

// ---------------- attention coefficients from the INPUT ----------------
template<int INC>
__global__ __launch_bounds__(256) void k_attn_in(
    const float* __restrict__ X, const float* __restrict__ wsF, const float* __restrict__ wdF,
    float* __restrict__ aS, float* __restrict__ aD){
  int v = blockIdx.x*4 + (threadIdx.x >> 6);
  int lane = threadIdx.x & 63;
  float x0 = X[(size_t)v*INC + lane];
  float x1 = (INC == 128) ? X[(size_t)v*INC + 64 + lane] : 0.f;
  float s[4], d[4];
  #pragma unroll
  for (int h = 0; h < 4; ++h){
    s[h] = x0*wsF[h*INC + lane];
    d[h] = x0*wdF[h*INC + lane];
    if constexpr (INC == 128){
      s[h] = fmaf(x1, wsF[h*INC + 64 + lane], s[h]);
      d[h] = fmaf(x1, wdF[h*INC + 64 + lane], d[h]);
    }
  }
  #pragma unroll
  for (int off = 32; off; off >>= 1){
    #pragma unroll
    for (int h = 0; h < 4; ++h){
      s[h] += __shfl_xor(s[h], off);
      d[h] += __shfl_xor(d[h], off);
    }
  }
  if (lane == 0){
    *(float4*)&aS[v*4] = make_float4(s[0], s[1], s[2], s[3]);
    *(float4*)&aD[v*4] = make_float4(d[0], d[1], d[2], d[3]);
  }
}

// ---------------- fused GAT: lane-parallel exp -> LDS, 8-deep gather accumulate ----------------
template<int INC>   // 128 (e3) or 64 (d3)
__global__ __launch_bounds__(256) void k_gat_fused(
    const float* __restrict__ X, const int* __restrict__ csr,
    const float* __restrict__ aS, const float* __restrict__ aD,
    const int* __restrict__ row_start, unsigned short* __restrict__ outp){
  __shared__ float4 sF[4][64];
  int wv = threadIdx.x >> 6;
  int v = blockIdx.x*4 + wv;
  int lane = threadIdx.x & 63;
  int s = __builtin_amdgcn_readfirstlane(row_start[v]);
  int e = __builtin_amdgcn_readfirstlane(row_start[v+1]);
  const int c2 = lane*2;

  float4 tD = *(const float4*)&aD[v*4];
  float ad0=tD.x, ad1=tD.y, ad2=tD.z, ad3=tD.w;
  float4 tS = *(const float4*)&aS[v*4];

  float sd0=0.f, sd1=0.f, sd2=0.f, sd3=0.f;
  float2 acc0={0,0}, acc1={0,0}, acc2={0,0}, acc3={0,0};
  float ac0=0.f, ac1=0.f, ac2=0.f, ac3=0.f;

  for (int base = s; base < e; base += 64){
    int i = base + lane;
    float4 f = {0.f, 0.f, 0.f, 0.f};
    if (i < e){
      int u = csr[i];
      float4 a4 = *(const float4*)&aS[u*4];
      f.x = __expf(lrelu02(a4.x+ad0));
      f.y = __expf(lrelu02(a4.y+ad1));
      f.z = __expf(lrelu02(a4.z+ad2));
      f.w = __expf(lrelu02(a4.w+ad3));
      sd0 += f.x; sd1 += f.y; sd2 += f.z; sd3 += f.w;
    }
    sF[wv][lane] = f;    // same-wave producer/consumer: no barrier needed
    int cnt = min(64, e - base);
    int j = 0;
    for (; j + 8 <= cnt; j += 8){
      int u0=csr[base+j],   u1=csr[base+j+1], u2=csr[base+j+2], u3=csr[base+j+3];
      int u4=csr[base+j+4], u5=csr[base+j+5], u6=csr[base+j+6], u7=csr[base+j+7];
      float4 f0=sF[wv][j],   f1=sF[wv][j+1], f2=sF[wv][j+2], f3=sF[wv][j+3];
      float4 f4=sF[wv][j+4], f5=sF[wv][j+5], f6=sF[wv][j+6], f7=sF[wv][j+7];
      if constexpr (INC == 128){
        float2 x0 = *(const float2*)&X[(size_t)u0*128 + c2];
        float2 x1 = *(const float2*)&X[(size_t)u1*128 + c2];
        float2 x2 = *(const float2*)&X[(size_t)u2*128 + c2];
        float2 x3 = *(const float2*)&X[(size_t)u3*128 + c2];
        float2 x4 = *(const float2*)&X[(size_t)u4*128 + c2];
        float2 x5 = *(const float2*)&X[(size_t)u5*128 + c2];
        float2 x6 = *(const float2*)&X[(size_t)u6*128 + c2];
        float2 x7 = *(const float2*)&X[(size_t)u7*128 + c2];
        acc0.x=fmaf(f0.x,x0.x,acc0.x); acc0.y=fmaf(f0.x,x0.y,acc0.y);
        acc1.x=fmaf(f0.y,x0.x,acc1.x); acc1.y=fmaf(f0.y,x0.y,acc1.y);
        acc2.x=fmaf(f0.z,x0.x,acc2.x); acc2.y=fmaf(f0.z,x0.y,acc2.y);
        acc3.x=fmaf(f0.w,x0.x,acc3.x); acc3.y=fmaf(f0.w,x0.y,acc3.y);
        acc0.x=fmaf(f1.x,x1.x,acc0.x); acc0.y=fmaf(f1.x,x1.y,acc0.y);
        acc1.x=fmaf(f1.y,x1.x,acc1.x); acc1.y=fmaf(f1.y,x1.y,acc1.y);
        acc2.x=fmaf(f1.z,x1.x,acc2.x); acc2.y=fmaf(f1.z,x1.y,acc2.y);
        acc3.x=fmaf(f1.w,x1.x,acc3.x); acc3.y=fmaf(f1.w,x1.y,acc3.y);
        acc0.x=fmaf(f2.x,x2.x,acc0.x); acc0.y=fmaf(f2.x,x2.y,acc0.y);
        acc1.x=fmaf(f2.y,x2.x,acc1.x); acc1.y=fmaf(f2.y,x2.y,acc1.y);
        acc2.x=fmaf(f2.z,x2.x,acc2.x); acc2.y=fmaf(f2.z,x2.y,acc2.y);
        acc3.x=fmaf(f2.w,x2.x,acc3.x); acc3.y=fmaf(f2.w,x2.y,acc3.y);
        acc0.x=fmaf(f3.x,x3.x,acc0.x); acc0.y=fmaf(f3.x,x3.y,acc0.y);
        acc1.x=fmaf(f3.y,x3.x,acc1.x); acc1.y=fmaf(f3.y,x3.y,acc1.y);
        acc2.x=fmaf(f3.z,x3.x,acc2.x); acc2.y=fmaf(f3.z,x3.y,acc2.y);
        acc3.x=fmaf(f3.w,x3.x,acc3.x); acc3.y=fmaf(f3.w,x3.y,acc3.y);
        acc0.x=fmaf(f4.x,x4.x,acc0.x); acc0.y=fmaf(f4.x,x4.y,acc0.y);
        acc1.x=fmaf(f4.y,x4.x,acc1.x); acc1.y=fmaf(f4.y,x4.y,acc1.y);
        acc2.x=fmaf(f4.z,x4.x,acc2.x); acc2.y=fmaf(f4.z,x4.y,acc2.y);
        acc3.x=fmaf(f4.w,x4.x,acc3.x); acc3.y=fmaf(f4.w,x4.y,acc3.y);
        acc0.x=fmaf(f5.x,x5.x,acc0.x); acc0.y=fmaf(f5.x,x5.y,acc0.y);
        acc1.x=fmaf(f5.y,x5.x,acc1.x); acc1.y=fmaf(f5.y,x5.y,acc1.y);
        acc2.x=fmaf(f5.z,x5.x,acc2.x); acc2.y=fmaf(f5.z,x5.y,acc2.y);
        acc3.x=fmaf(f5.w,x5.x,acc3.x); acc3.y=fmaf(f5.w,x5.y,acc3.y);
        acc0.x=fmaf(f6.x,x6.x,acc0.x); acc0.y=fmaf(f6.x,x6.y,acc0.y);
        acc1.x=fmaf(f6.y,x6.x,acc1.x); acc1.y=fmaf(f6.y,x6.y,acc1.y);
        acc2.x=fmaf(f6.z,x6.x,acc2.x); acc2.y=fmaf(f6.z,x6.y,acc2.y);
        acc3.x=fmaf(f6.w,x6.x,acc3.x); acc3.y=fmaf(f6.w,x6.y,acc3.y);
        acc0.x=fmaf(f7.x,x7.x,acc0.x); acc0.y=fmaf(f7.x,x7.y,acc0.y);
        acc1.x=fmaf(f7.y,x7.x,acc1.x); acc1.y=fmaf(f7.y,x7.y,acc1.y);
        acc2.x=fmaf(f7.z,x7.x,acc2.x); acc2.y=fmaf(f7.z,x7.y,acc2.y);
        acc3.x=fmaf(f7.w,x7.x,acc3.x); acc3.y=fmaf(f7.w,x7.y,acc3.y);
      } else {
        float x0 = X[(size_t)u0*64 + lane];
        float x1 = X[(size_t)u1*64 + lane];
        float x2 = X[(size_t)u2*64 + lane];
        float x3 = X[(size_t)u3*64 + lane];
        float x4 = X[(size_t)u4*64 + lane];
        float x5 = X[(size_t)u5*64 + lane];
        float x6 = X[(size_t)u6*64 + lane];
        float x7 = X[(size_t)u7*64 + lane];
        ac0=fmaf(f0.x,x0,ac0); ac1=fmaf(f0.y,x0,ac1); ac2=fmaf(f0.z,x0,ac2); ac3=fmaf(f0.w,x0,ac3);
        ac0=fmaf(f1.x,x1,ac0); ac1=fmaf(f1.y,x1,ac1); ac2=fmaf(f1.z,x1,ac2); ac3=fmaf(f1.w,x1,ac3);
        ac0=fmaf(f2.x,x2,ac0); ac1=fmaf(f2.y,x2,ac1); ac2=fmaf(f2.z,x2,ac2); ac3=fmaf(f2.w,x2,ac3);
        ac0=fmaf(f3.x,x3,ac0); ac1=fmaf(f3.y,x3,ac1); ac2=fmaf(f3.z,x3,ac2); ac3=fmaf(f3.w,x3,ac3);
        ac0=fmaf(f4.x,x4,ac0); ac1=fmaf(f4.y,x4,ac1); ac2=fmaf(f4.z,x4,ac2); ac3=fmaf(f4.w,x4,ac3);
        ac0=fmaf(f5.x,x5,ac0); ac1=fmaf(f5.y,x5,ac1); ac2=fmaf(f5.z,x5,ac2); ac3=fmaf(f5.w,x5,ac3);
        ac0=fmaf(f6.x,x6,ac0); ac1=fmaf(f6.y,x6,ac1); ac2=fmaf(f6.z,x6,ac2); ac3=fmaf(f6.w,x6,ac3);
        ac0=fmaf(f7.x,x7,ac0); ac1=fmaf(f7.y,x7,ac1); ac2=fmaf(f7.z,x7,ac2); ac3=fmaf(f7.w,x7,ac3);
      }
    }
    for (; j + 4 <= cnt; j += 4){
      int u0=csr[base+j], u1=csr[base+j+1], u2=csr[base+j+2], u3=csr[base+j+3];
      float4 f0=sF[wv][j], f1=sF[wv][j+1], f2=sF[wv][j+2], f3=sF[wv][j+3];
      if constexpr (INC == 128){
        float2 x0 = *(const float2*)&X[(size_t)u0*128 + c2];
        float2 x1 = *(const float2*)&X[(size_t)u1*128 + c2];
        float2 x2 = *(const float2*)&X[(size_t)u2*128 + c2];
        float2 x3 = *(const float2*)&X[(size_t)u3*128 + c2];
        acc0.x=fmaf(f0.x,x0.x,acc0.x); acc0.y=fmaf(f0.x,x0.y,acc0.y);
        acc1.x=fmaf(f0.y,x0.x,acc1.x); acc1.y=fmaf(f0.y,x0.y,acc1.y);
        acc2.x=fmaf(f0.z,x0.x,acc2.x); acc2.y=fmaf(f0.z,x0.y,acc2.y);
        acc3.x=fmaf(f0.w,x0.x,acc3.x); acc3.y=fmaf(f0.w,x0.y,acc3.y);
        acc0.x=fmaf(f1.x,x1.x,acc0.x); acc0.y=fmaf(f1.x,x1.y,acc0.y);
        acc1.x=fmaf(f1.y,x1.x,acc1.x); acc1.y=fmaf(f1.y,x1.y,acc1.y);
        acc2.x=fmaf(f1.z,x1.x,acc2.x); acc2.y=fmaf(f1.z,x1.y,acc2.y);
        acc3.x=fmaf(f1.w,x1.x,acc3.x); acc3.y=fmaf(f1.w,x1.y,acc3.y);
        acc0.x=fmaf(f2.x,x2.x,acc0.x); acc0.y=fmaf(f2.x,x2.y,acc0.y);
        acc1.x=fmaf(f2.y,x2.x,acc1.x); acc1.y=fmaf(f2.y,x2.y,acc1.y);
        acc2.x=fmaf(f2.z,x2.x,acc2.x); acc2.y=fmaf(f2.z,x2.y,acc2.y);
        acc3.x=fmaf(f2.w,x2.x,acc3.x); acc3.y=fmaf(f2.w,x2.y,acc3.y);
        acc0.x=fmaf(f3.x,x3.x,acc0.x); acc0.y=fmaf(f3.x,x3.y,acc0.y);
        acc1.x=fmaf(f3.y,x3.x,acc1.x); acc1.y=fmaf(f3.y,x3.y,acc1.y);
        acc2.x=fmaf(f3.z,x3.x,acc2.x); acc2.y=fmaf(f3.z,x3.y,acc2.y);
        acc3.x=fmaf(f3.w,x3.x,acc3.x); acc3.y=fmaf(f3.w,x3.y,acc3.y);
      } else {
        float x0 = X[(size_t)u0*64 + lane];
        float x1 = X[(size_t)u1*64 + lane];
        float x2 = X[(size_t)u2*64 + lane];
        float x3 = X[(size_t)u3*64 + lane];
        ac0=fmaf(f0.x,x0,ac0); ac1=fmaf(f0.y,x0,ac1); ac2=fmaf(f0.z,x0,ac2); ac3=fmaf(f0.w,x0,ac3);
        ac0=fmaf(f1.x,x1,ac0); ac1=fmaf(f1.y,x1,ac1); ac2=fmaf(f1.z,x1,ac2); ac3=fmaf(f1.w,x1,ac3);
        ac0=fmaf(f2.x,x2,ac0); ac1=fmaf(f2.y,x2,ac1); ac2=fmaf(f2.z,x2,ac2); ac3=fmaf(f2.w,x2,ac3);
        ac0=fmaf(f3.x,x3,ac0); ac1=fmaf(f3.y,x3,ac1); ac2=fmaf(f3.z,x3,ac2); ac3=fmaf(f3.w,x3,ac3);
      }
    }
    for (; j < cnt; ++j){
      int u = csr[base+j];
      float4 f4 = sF[wv][j];
      if constexpr (INC == 128){
        float2 xu = *(const float2*)&X[(size_t)u*128 + c2];
        acc0.x=fmaf(f4.x,xu.x,acc0.x); acc0.y=fmaf(f4.x,xu.y,acc0.y);
        acc1.x=fmaf(f4.y,xu.x,acc1.x); acc1.y=fmaf(f4.y,xu.y,acc1.y);
        acc2.x=fmaf(f4.z,xu.x,acc2.x); acc2.y=fmaf(f4.z,xu.y,acc2.y);
        acc3.x=fmaf(f4.w,xu.x,acc3.x); acc3.y=fmaf(f4.w,xu.y,acc3.y);
      } else {
        float xu = X[(size_t)u*64 + lane];
        ac0=fmaf(f4.x,xu,ac0); ac1=fmaf(f4.y,xu,ac1); ac2=fmaf(f4.z,xu,ac2); ac3=fmaf(f4.w,xu,ac3);
      }
    }
  }

  #pragma unroll
  for (int off = 32; off; off >>= 1){
    sd0 += __shfl_xor(sd0, off);
    sd1 += __shfl_xor(sd1, off);
    sd2 += __shfl_xor(sd2, off);
    sd3 += __shfl_xor(sd3, off);
  }
  float es0=__expf(lrelu02(tS.x+ad0)), es1=__expf(lrelu02(tS.y+ad1));
  float es2=__expf(lrelu02(tS.z+ad2)), es3=__expf(lrelu02(tS.w+ad3));
  float r0=1.f/(sd0+es0), r1=1.f/(sd1+es1), r2=1.f/(sd2+es2), r3=1.f/(sd3+es3);

  if constexpr (INC == 128){
    float2 xv = *(const float2*)&X[(size_t)v*128 + c2];
    const size_t loOff = (size_t)Nn*512;
    float ox, oy; unsigned short h0,l0,h1,l1;
    ox=(acc0.x+es0*xv.x)*r0; oy=(acc0.y+es0*xv.y)*r0;
    packhl(ox,h0,l0); packhl(oy,h1,l1);
    *(unsigned int*)&outp[(size_t)v*512 +   0 + c2] = (unsigned)h0|((unsigned)h1<<16);
    *(unsigned int*)&outp[(size_t)v*512 +   0 + c2 + loOff] = (unsigned)l0|((unsigned)l1<<16);
    ox=(acc1.x+es1*xv.x)*r1; oy=(acc1.y+es1*xv.y)*r1;
    packhl(ox,h0,l0); packhl(oy,h1,l1);
    *(unsigned int*)&outp[(size_t)v*512 + 128 + c2] = (unsigned)h0|((unsigned)h1<<16);
    *(unsigned int*)&outp[(size_t)v*512 + 128 + c2 + loOff] = (unsigned)l0|((unsigned)l1<<16);
    ox=(acc2.x+es2*xv.x)*r2; oy=(acc2.y+es2*xv.y)*r2;
    packhl(ox,h0,l0); packhl(oy,h1,l1);
    *(unsigned int*)&outp[(size_t)v*512 + 256 + c2] = (unsigned)h0|((unsigned)h1<<16);
    *(unsigned int*)&outp[(size_t)v*512 + 256 + c2 + loOff] = (unsigned)l0|((unsigned)l1<<16);
    ox=(acc3.x+es3*xv.x)*r3; oy=(acc3.y+es3*xv.y)*r3;
    packhl(ox,h0,l0); packhl(oy,h1,l1);
    *(unsigned int*)&outp[(size_t)v*512 + 384 + c2] = (unsigned)h0|((unsigned)h1<<16);
    *(unsigned int*)&outp[(size_t)v*512 + 384 + c2 + loOff] = (unsigned)l0|((unsigned)l1<<16);
  } else {
    float xv = X[(size_t)v*64 + lane];
    const size_t loOff = (size_t)Nn*256;
    unsigned short hh,ll;
    float o;
    o = (ac0+es0*xv)*r0; packhl(o,hh,ll);
    outp[(size_t)v*256 +   0 + lane] = hh; outp[(size_t)v*256 +   0 + lane + loOff] = ll;
    o = (ac1+es1*xv)*r1; packhl(o,hh,ll);
    outp[(size_t)v*256 +  64 + lane] = hh; outp[(size_t)v*256 +  64 + lane + loOff] = ll;
    o = (ac2+es2*xv)*r2; packhl(o,hh,ll);
    outp[(size_t)v*256 + 128 + lane] = hh; outp[(size_t)v*256 + 128 + lane + loOff] = ll;
    o = (ac3+es3*xv)*r3; packhl(o,hh,ll);
    outp[(size_t)v*256 + 192 + lane] = hh; outp[(size_t)v*256 + 192 + lane + loOff] = ll;
  }
}

// ---------------- MFMA GEMM: BM=64, BN=64, BK=32; 4 waves, wave = 16 rows x 64 cols ----------------
template<int K, int J, int Jh, int EPI>
__global__ __launch_bounds__(256) void k_gemm(
    const unsigned short* __restrict__ Ahi, int lda,
    const unsigned short* __restrict__ Wp,
    const float* __restrict__ bias,
    float* __restrict__ outf, unsigned short* __restrict__ outp){
  __shared__ unsigned short sAhi[4*64*8], sAlo[4*64*8];
  __shared__ unsigned short sBhi[4*64*8], sBlo[4*64*8];

  const int tid  = threadIdx.x;
  const int lane = tid & 63, w = tid >> 6;
  const int rb = blockIdx.x;
  const int colbase = blockIdx.z*Jh + blockIdx.y*64;
  const int akoff   = blockIdx.z*K;
  const size_t AloOff = (size_t)Nn*lda;
  const size_t WloOff = (size_t)K*J;

  f32x4 accH[4] = {{0,0,0,0},{0,0,0,0},{0,0,0,0},{0,0,0,0}};
  f32x4 accM[4] = {{0,0,0,0},{0,0,0,0},{0,0,0,0},{0,0,0,0}};

  const int arow = tid >> 2;
  const int akq  = (tid & 3) * 8;
  int agrow = rb*64 + arow; if (agrow >= Nn) agrow = Nn - 1;
  const unsigned short* Ag = Ahi + (size_t)agrow*lda + akoff + akq;
  const int aw_idx = (((arow>>4)*4 + (akq>>3))*16 + (arow&15))*8;
  const int bcol = tid & 63;
  const int bkg  = tid >> 6;
  const int bw_idx = (((bcol>>4)*4 + bkg)*16 + (bcol&15))*8;
  const int cf_g  = (colbase>>4) + (bcol>>4);
  const size_t wbase = ((size_t)cf_g*(K/8)*16 + (size_t)(bcol&15))*8;

  #pragma unroll 1
  for (int ks = 0; ks < K/32; ++ks){
    if (ks) __syncthreads();
    {
      const unsigned short* p = Ag + ks*32;
      uint4 hv = *(const uint4*)p;
      uint4 lv = *(const uint4*)(p + AloOff);
      *(uint4*)&sAhi[aw_idx] = hv;
      *(uint4*)&sAlo[aw_idx] = lv;
    }
    {
      size_t goff = wbase + (size_t)(ks*4 + bkg)*128;
      uint4 hv = *(const uint4*)&Wp[goff];
      uint4 lv = *(const uint4*)&Wp[goff + WloOff];
      *(uint4*)&sBhi[bw_idx] = hv;
      *(uint4*)&sBlo[bw_idx] = lv;
    }
    __syncthreads();

    half8 aH = *(const half8*)&sAhi[(w*64 + lane)*8];
    half8 aL = *(const half8*)&sAlo[(w*64 + lane)*8];
    #pragma unroll
    for (int cf = 0; cf < 4; ++cf){
      half8 bH = *(const half8*)&sBhi[(cf*64 + lane)*8];
      half8 bL = *(const half8*)&sBlo[(cf*64 + lane)*8];
      accH[cf] = __builtin_amdgcn_mfma_f32_16x16x32_f16(aH, bH, accH[cf], 0, 0, 0);
      accM[cf] = __builtin_amdgcn_mfma_f32_16x16x32_f16(aH, bL, accM[cf], 0, 0, 0);
      accM[cf] = __builtin_amdgcn_mfma_f32_16x16x32_f16(aL, bH, accM[cf], 0, 0, 0);
    }
  }

  #pragma unroll
  for (int cf = 0; cf < 4; ++cf){
    int col = colbase + cf*16 + (lane & 15);
    float bv = (EPI >= 1) ? bias[col] : 0.f;
    #pragma unroll
    for (int r = 0; r < 4; ++r){
      int row = rb*64 + w*16 + ((lane>>4)*4 + r);
      if (row < Nn){
        float v = accH[cf][r] + accM[cf][r]*(1.0f/2048.0f);
        if constexpr (EPI >= 1) v = fmaxf(v + bv, 0.f);
        if constexpr (EPI == 2){
          unsigned short hh, ll; packhl(v, hh, ll);
          outp[(size_t)row*J + col] = hh;
          outp[(size_t)row*J + col + (size_t)Nn*J] = ll;
        } else {
          outf[(size_t)row*J + col] = v;
        }
      }
    }
  }
}

// ---------------- final 128 -> 4 matmul (+bias), one wave per row ----------------
__global__ __launch_bounds__(256) void k_mm_fin(
    const float* __restrict__ A, const float* __restrict__ W,
    const float* __restrict__ bias, float* __restrict__ out){
  int row = blockIdx.x*4 + (threadIdx.x >> 6);
  int lane = threadIdx.x & 63;
  float a0 = A[(size_t)row*128 + lane];
  float a1 = A[(size_t)row*128 + 64 + lane];
  float4 w0 = ((const float4*)W)[lane];
  float4 w1 = ((const float4*)W)[64 + lane];
  float p0 = fmaf(a1, w1.x, a0*w0.x);
  float p1 = fmaf(a1, w1.y, a0*w0.y);
  float p2 = fmaf(a1, w1.z, a0*w0.z);
  float p3 = fmaf(a1, w1.w, a0*w0.w);
  #pragma unroll
  for (int off = 32; off; off >>= 1){
    p0 += __shfl_xor(p0, off);
    p1 += __shfl_xor(p1, off);
    p2 += __shfl_xor(p2, off);
    p3 += __shfl_xor(p3, off);
  }
  if (lane == 0){
    float4 bv = *(const float4*)bias;
    *(float4*)&out[(size_t)row*4] = make_float4(p0+bv.x, p1+bv.y, p2+bv.z, p3+bv.w);
  }
}

// ---------------- launch ----------------
extern "C" void kernel_launch(void* const* d_in, const int* in_sizes, int n_in,
                              void* d_out, int out_size, void* d_ws, size_t ws_size,
                              hipStream_t stream){
  const float* x     = (const float*)d_in[0];
  const int*   ei    = (const int*)  d_in[1];
  const float* w_e1  = (const float*)d_in[2];
  const float* b_e1  = (const float*)d_in[3];
  const float* w_e2  = (const float*)d_in[4];
  const float* b_e2  = (const float*)d_in[5];
  const float* w_e3  = (const float*)d_in[6];
  const float* as_e3 = (const float*)d_in[7];
  const float* ad_e3 = (const float*)d_in[8];
  const float* b_e3  = (const float*)d_in[9];
  const float* w_d1  = (const float*)d_in[10];
  const float* b_d1  = (const float*)d_in[11];
  const float* w_d2  = (const float*)d_in[12];
  const float* b_d2  = (const float*)d_in[13];
  const float* w_d3  = (const float*)d_in[14];
  const float* as_d3 = (const float*)d_in[15];
  const float* ad_d3 = (const float*)d_in[16];
  const float* b_d3  = (const float*)d_in[17];
  const float* w_fc1 = (const float*)d_in[18];
  const float* b_fc1 = (const float*)d_in[19];
  const float* w_fc2 = (const float*)d_in[20];
  const float* b_fc2 = (const float*)d_in[21];
  const float* w_fin = (const float*)d_in[22];
  const float* b_fin = (const float*)d_in[23];

  char* ws = (char*)d_ws;
  size_t off = 0;
  auto alloc = [&](size_t bytes)->char*{
    char* p = ws + off;
    off += (bytes + 255) & ~size_t(255);
    return p;
  };
  int*   cnt       = (int*)  alloc((size_t)Nn*4);      // cnt+fill contiguous: one memset
  int*   fill      = (int*)  alloc((size_t)Nn*4);
  int*   row_start = (int*)  alloc((size_t)(Nn+1)*4);
  int*   csr       = (int*)  alloc((size_t)Ee*4);
  float* dinv      = (float*)alloc((size_t)Nn*4);
  int2*  erec      = (int2*) alloc((size_t)Ee*8);
  float* aSb       = (float*)alloc((size_t)Nn*16);
  float* aDb       = (float*)alloc((size_t)Nn*16);
  float* wsF_e3    = (float*)alloc(4*128*4);
  float* wdF_e3    = (float*)alloc(4*128*4);
  float* wsF_d3    = (float*)alloc(4*64*4);
  float* wdF_d3    = (float*)alloc(4*64*4);
  // fragment-packed weights (hi then lo)
  unsigned short* wp_e1  = (unsigned short*)alloc((size_t)32*64*4);
  unsigned short* wp_e2  = (unsigned short*)alloc((size_t)64*128*4);
  unsigned short* wp_e3  = (unsigned short*)alloc((size_t)128*512*4);
  unsigned short* wp_d1  = (unsigned short*)alloc((size_t)512*128*4);
  unsigned short* wp_d2  = (unsigned short*)alloc((size_t)128*64*4);
  unsigned short* wp_d3  = (unsigned short*)alloc((size_t)64*256*4);
  unsigned short* wp_fc1 = (unsigned short*)alloc((size_t)256*256*4);
  unsigned short* wp_fc2 = (unsigned short*)alloc((size_t)256*128*4);
  // activations
  unsigned short* P0 = (unsigned short*)alloc((size_t)Nn*32*4);
  float* X1 = (float*)alloc((size_t)Nn*64*4);
  float* X2 = (float*)alloc((size_t)Nn*128*4);
  unsigned short* S1 = (unsigned short*)alloc((size_t)Nn*512*4);
  unsigned short* S2 = (unsigned short*)alloc((size_t)Nn*512*4);
  char*  S3 = alloc((size_t)Nn*128*4);

  const int* srcp = ei;
  const int* dstp = ei + Ee;

  hipMemsetAsync(cnt, 0, (size_t)(((size_t)Nn*4 + 255) & ~size_t(255)) + (size_t)Nn*4, stream);

  PrepArgs pa;
  pa.w_e1=w_e1; pa.w_e2=w_e2; pa.w_e3=w_e3; pa.w_d1=w_d1;
  pa.w_d2=w_d2; pa.w_d3=w_d3; pa.w_fc1=w_fc1; pa.w_fc2=w_fc2;
  pa.p_e1=wp_e1; pa.p_e2=wp_e2; pa.p_e3=wp_e3; pa.p_d1=wp_d1;
  pa.p_d2=wp_d2; pa.p_d3=wp_d3; pa.p_fc1=wp_fc1; pa.p_fc2=wp_fc2;
  pa.as_e3=as_e3; pa.ad_e3=ad_e3; pa.as_d3=as_d3; pa.ad_d3=ad_d3;
  pa.wsF_e3=wsF_e3; pa.wdF_e3=wdF_e3; pa.wsF_d3=wsF_d3; pa.wdF_d3=wdF_d3;
  pa.dst=dstp; pa.cnt=cnt;
  k_init<<<2285, 256, 0, stream>>>(pa);   // 1035 blocks prep + 1250 blocks edge-count

  k_scan<<<1, 1024, 0, stream>>>(cnt, row_start, dinv);
  k_scatter<<<(Ee+255)/256, 256, 0, stream>>>(srcp, dstp, row_start, fill, csr, dinv, erec);

  // encoder1: x1 = relu(agg(x) @ W1 + b1)
  k_gcn_agg<32,2><<<Nn/4, 256, 0, stream>>>(x, dinv, row_start, erec, nullptr, nullptr, nullptr, P0);
  k_gemm<32,64,64,1><<<dim3(313,1,1), 256, 0, stream>>>(P0, 32, wp_e1, b_e1, X1, nullptr);
  // encoder2: x2 = relu(agg(x1) @ W2 + b2)
  k_gcn_agg<64,2><<<Nn/4, 256, 0, stream>>>(X1, dinv, row_start, erec, nullptr, nullptr, nullptr, (unsigned short*)S3);
  k_gemm<64,128,128,1><<<dim3(313,2,1), 256, 0, stream>>>((unsigned short*)S3, 64, wp_e2, b_e2, X2, nullptr);
  // encoder3 (GAT): x3 = relu(headmm(gat_agg(x2)) + b3)
  k_attn_in<128><<<Nn/4, 256, 0, stream>>>(X2, wsF_e3, wdF_e3, aSb, aDb);
  k_gat_fused<128><<<Nn/4, 256, 0, stream>>>(X2, csr, aSb, aDb, row_start, S1);
  k_gemm<128,512,128,2><<<dim3(313,2,4), 256, 0, stream>>>(S1, 512, wp_e3, b_e3, nullptr, S2);
  // decoder1: h4 = relu(agg(x3 @ Wd1) + bd1) + x2
  k_gemm<512,128,128,0><<<dim3(313,2,1), 256, 0, stream>>>(S2, 512, wp_d1, nullptr, (float*)S3, nullptr);
  k_gcn_agg<128,3><<<Nn/4, 256, 0, stream>>>((float*)S3, dinv, row_start, erec, b_d1, X2, nullptr, S1);
  // decoder2: h5 = relu(agg(h4 @ Wd2) + bd2) + x1
  k_gemm<128,64,64,0><<<dim3(313,1,1), 256, 0, stream>>>(S1, 128, wp_d2, nullptr, (float*)S2, nullptr);
  k_gcn_agg<64,1><<<Nn/4, 256, 0, stream>>>((float*)S2, dinv, row_start, erec, b_d2, X1, (float*)S3, nullptr);
  // decoder3 (GAT): h6 = relu(headmm(gat_agg(h5)) + bd3)
  k_attn_in<64><<<Nn/4, 256, 0, stream>>>((float*)S3, wsF_d3, wdF_d3, aSb, aDb);
  k_gat_fused<64><<<Nn/4, 256, 0, stream>>>((float*)S3, csr, aSb, aDb, row_start, S1);
  k_gemm<64,256,64,2><<<dim3(313,1,4), 256, 0, stream>>>(S1, 256, wp_d3, b_d3, nullptr, S2);
  // MLP head
  k_gemm<256,256,256,2><<<dim3(313,4,1), 256, 0, stream>>>(S2, 256, wp_fc1, b_fc1, nullptr, S1);
  k_gemm<256,128,128,1><<<dim3(313,2,1), 256, 0, stream>>>(S1, 256, wp_fc2, b_fc2, (float*)S2, nullptr);
  k_mm_fin<<<Nn/4, 256, 0, stream>>>((float*)S2, w_fin, b_fin, (float*)d_out);
}